// Round 11
// baseline (191.418 us; speedup 1.0000x reference)
//
#include <hip/hip_runtime.h>
#include <hip/hip_bf16.h>

typedef unsigned short u16;
typedef _Float16 h16;
typedef __attribute__((ext_vector_type(8))) h16 h8;     // 8 x f16 (4 VGPRs)
typedef __attribute__((ext_vector_type(4))) u16 us4;    // 4 x u16
typedef __attribute__((ext_vector_type(4))) float f4;   // MFMA accumulator

#define DEVFN __device__ __forceinline__

constexpr int kN = 384;
constexpr int kL = 64;
constexpr int kMaxP = kN * 48;       // 18432 worst-case in-block pairs
constexpr int kOutCols = 2148;       // 1024 (x) + 1024 (att out) + 100 (e100)
constexpr float kS = 64.f;           // residual scale (keeps f16 normal; /64 planes may flush, budgeted)
constexpr float kSInv = 1.f / 64.f;

union HU { h16 h; u16 u; };
DEVFN u16 f2h(float f) { HU c; c.h = (h16)f; return c.u; }
DEVFN float h2f(u16 b) { HU c; c.u = b; return (float)c.h; }

DEVFN f4 mfma16h(h8 a, h8 b, f4 c) {
  return __builtin_amdgcn_mfma_f32_16x16x32_f16(a, b, c, 0, 0, 0);
}

DEVFN h8 pack8h(float4 x0, float4 x1) {
  h8 a;
  a[0] = (h16)x0.x; a[1] = (h16)x0.y; a[2] = (h16)x0.z; a[3] = (h16)x0.w;
  a[4] = (h16)x1.x; a[5] = (h16)x1.y; a[6] = (h16)x1.z; a[7] = (h16)x1.w;
  return a;
}

DEVFN h8 mulInv64(h8 a) {   // exact exponent shift (subnormal flush budgeted)
  #pragma unroll
  for (int j = 0; j < 8; ++j) a[j] = (h16)(a[j] * (h16)0.015625f);
  return a;
}

// f32 sincos with FMA 2-word reduction (non-critical e100 path)
DEVFN void fsincos(float ang, float& s, float& c) {
  float n = rintf(ang * 0.15915494309189535f);
  const float PI2_HI = 6.2831854820251465f;
  const float PI2_LO = -1.7484555e-07f;
  float r = fmaf(-n, PI2_HI, ang);
  r = fmaf(-n, PI2_LO, r);
  s = __sinf(r);
  c = __cosf(r);
}

// =================== L1: per-row block extents ===================
__global__ __launch_bounds__(64) void k_ext(const float* __restrict__ bm,
                                            int* __restrict__ row_start,
                                            int* __restrict__ row_len) {
  int i = blockIdx.x, lane = threadIdx.x;
  int mn = kN, mx = -1;
  #pragma unroll
  for (int jb = 0; jb < kN; jb += 64) {
    float m = bm[(size_t)i * kN + jb + lane];
    if (m > 0.f) { mn = min(mn, jb + lane); mx = max(mx, jb + lane); }
  }
  #pragma unroll
  for (int off = 32; off > 0; off >>= 1) {
    mn = min(mn, __shfl_xor(mn, off));
    mx = max(mx, __shfl_xor(mx, off));
  }
  if (lane == 0) { row_start[i] = mn; row_len[i] = mx - mn + 1; }
}

// =================== L2: exclusive scan of row_len -> row_off, Ptr ===================
__global__ __launch_bounds__(64) void k_scan(const int* __restrict__ row_len,
                                             int* __restrict__ row_off,
                                             int* __restrict__ Ptr) {
  int lane = threadIdx.x;
  int s[6], tot = 0;
  #pragma unroll
  for (int r = 0; r < 6; ++r) { s[r] = tot; tot += row_len[lane * 6 + r]; }
  int run = tot;
  #pragma unroll
  for (int off = 1; off < 64; off <<= 1) {
    int u = __shfl_up(run, off);
    if (lane >= off) run += u;
  }
  int excl = run - tot;
  #pragma unroll
  for (int r = 0; r < 6; ++r) row_off[lane * 6 + r] = excl + s[r];
  if (lane == 63) Ptr[0] = excl + tot;
}

// ---------------- fill flat pair list (fallback path only) ----------------
__global__ __launch_bounds__(64) void k_fill(const int* __restrict__ row_start,
                                             const int* __restrict__ row_len,
                                             const int* __restrict__ row_off,
                                             int* __restrict__ pair_i,
                                             int* __restrict__ pair_j) {
  int i = blockIdx.x, lane = threadIdx.x;
  int s = row_start[i], len = row_len[i], off = row_off[i];
  if (lane < len) { pair_i[off + lane] = i; pair_j[off + lane] = s + lane; }
}

// =================== L3: cvt | mean | zero | emb (all independent, co-resident) =======
// grid: [0,512) cvt | [512,768) mean | [768,816) zero bias_acc | [816,10032) emb
__global__ __launch_bounds__(256) void k_big(
    const float* __restrict__ Wp1, u16* __restrict__ W1B,
    const float* __restrict__ Wp2, u16* __restrict__ w2h, u16* __restrict__ w2hd,
    u16* __restrict__ w2l64,
    const float* __restrict__ Wpre, u16* __restrict__ WpreH,
    const float* __restrict__ Wq, u16* __restrict__ WqH,
    const float* __restrict__ Wk, u16* __restrict__ WkH,
    const float* __restrict__ Wv, u16* __restrict__ WvH,
    const float* __restrict__ feats, const int* __restrict__ gidx,
    const float* __restrict__ cmask, float* __restrict__ mean,
    float* __restrict__ bias_acc,
    const int* __restrict__ Ptr, const int* __restrict__ row_start,
    const int* __restrict__ row_off, const float* __restrict__ bbox,
    u16* __restrict__ Ap) {
  int bid = blockIdx.x, t = threadIdx.x;
  if (bid < 512) {
    const int nW1 = 1048576, nW2 = 16384, nPre = 1048576, nQ = 131072;
    const int tot = nW1 + nW2 + nPre + 3 * nQ;
    for (int i = bid * 256 + t; i < tot; i += 512 * 256) {
      if (i < nW1) {
        int n = i >> 10, k = i & 1023;
        float x = Wp1[i]; u16 h = f2h(x);
        u16* row = W1B + (size_t)n * 3072;
        row[k] = h;
        row[1024 + k] = f2h(h2f(h) * kSInv);         // wh/64
        row[2048 + k] = f2h((x - h2f(h)) * kS);      // (w-wh)*64
      } else if (i < nW1 + nW2) {
        int j = i - nW1; float x = Wp2[j]; u16 h = f2h(x);
        w2h[j] = h;
        w2hd[j] = f2h(h2f(h) * kSInv);
        w2l64[j] = f2h((x - h2f(h)) * kS);
      } else if (i < nW1 + nW2 + nPre) {
        int j = i - nW1 - nW2; WpreH[j] = f2h(Wpre[j]);
      } else {
        int j = i - nW1 - nW2 - nPre;
        int a = j / nQ, r = j % nQ;
        const float* s = (a == 0) ? Wq : (a == 1) ? Wk : Wv;
        u16* d = (a == 0) ? WqH : (a == 1) ? WkH : WvH;
        d[r] = f2h(s[r]);
      }
    }
  } else if (bid < 768) {
    int e = bid - 512;
    float4 a = {0.f, 0.f, 0.f, 0.f};
    float ms = 0.f;
    for (int l = 0; l < kL; ++l) {
      float m = cmask[e * kL + l];
      ms += m;
      if (m > 0.f) {
        float4 v = *(const float4*)(feats + (size_t)gidx[e * kL + l] * 1024 + t * 4);
        a.x += v.x; a.y += v.y; a.z += v.z; a.w += v.w;
      }
    }
    float inv = 1.f / (ms + 1e-5f);
    float4 o = {a.x * inv, a.y * inv, a.z * inv, a.w * inv};
    *(float4*)(mean + (size_t)e * 1024 + t * 4) = o;
  } else if (bid < 816) {
    float4 z = {0.f, 0.f, 0.f, 0.f};
    for (int i4 = (bid - 768) * 256 + t; i4 < kMaxP * 16 / 4; i4 += 48 * 256)
      *(float4*)(bias_acc + (size_t)i4 * 4) = z;
  } else {
    int eb = bid - 816;                  // emb: 2 pairs per block
    int P = Ptr[0];
    int Pc = (P + 127) & ~127;
    if (eb * 2 >= Pc) return;
    __shared__ double As[16], Bs[16];
    __shared__ int roff[384], rstart[384];
    const double kCd = -13.287712379549449 / 256.0;
    if (t < 16) As[t] = exp2(kCd * (double)(t * 16));
    else if (t < 32) Bs[t - 16] = exp2(kCd * (double)(t - 16));
    for (int k = t; k < 384; k += 256) { roff[k] = row_off[k]; rstart[k] = row_start[k]; }
    __syncthreads();
    int p = eb * 2 + (t >> 7);
    int u = t & 127;
    int hseg = u >> 6;                   // 0: dc half, 1: dl half
    int f0 = (u & 63) * 4;               // 4 consecutive freqs per thread
    size_t obA = (size_t)p * 2048 + hseg * 512 + f0;   // A' row stride 2048: [eh | el64]
    if (p >= P) {
      us4 z = {0, 0, 0, 0};
      *(us4*)(Ap + obA) = z;        *(us4*)(Ap + obA + 256) = z;
      *(us4*)(Ap + obA + 1024) = z; *(us4*)(Ap + obA + 1280) = z;
      return;
    }
    int lo = 0, hi = 383;
    while (lo < hi) { int md = (lo + hi + 1) >> 1; if (roff[md] <= p) lo = md; else hi = md - 1; }
    int pi = lo, pj = rstart[lo] + (p - roff[lo]);
    double s0 = bbox[pi * 2], e0 = bbox[pi * 2 + 1];
    double s1 = bbox[pj * 2], e1 = bbox[pj * 2 + 1];
    double li = fmax(e0 - s0, 0.1), lj = fmax(e1 - s1, 0.1);
    double x = hseg ? log(lj / li) : (0.5 * (s0 + e0) - 0.5 * (s1 + e1)) / li;
    double x100 = 100.0 * x;
    const double INV2PI = 0.15915494309189535;
    const double TWOPI  = 6.283185307179586;
    us4 sh_, sl_, ch_, cl_;
    #pragma unroll
    for (int j = 0; j < 4; ++j) {
      int f = f0 + j;
      double ang = x100 * (As[f >> 4] * Bs[f & 15]);
      double nn = rint(ang * INV2PI);
      float rf = (float)fma(-nn, TWOPI, ang);
      float sv = __sinf(rf), cv = __cosf(rf);
      u16 hs = f2h(sv); sh_[j] = hs; sl_[j] = f2h((sv - h2f(hs)) * kS);
      u16 hc = f2h(cv); ch_[j] = hc; cl_[j] = f2h((cv - h2f(hc)) * kS);
    }
    *(us4*)(Ap + obA) = sh_;        *(us4*)(Ap + obA + 256) = ch_;
    *(us4*)(Ap + obA + 1024) = sl_; *(us4*)(Ap + obA + 1280) = cl_;
  }
}

// =================== L4: event = relu(mean @ Wpre^T + bpre) ===================
__global__ __launch_bounds__(256) void k_egemm(const float* __restrict__ mean,
                                               const u16* __restrict__ WpreH,
                                               const float* __restrict__ bpre,
                                               float* __restrict__ event) {
  int mt = blockIdx.x >> 4, nc = blockIdx.x & 15;
  int t = threadIdx.x;
  int w = t >> 6, lane = t & 63, lr = lane & 15, lg = lane >> 4;
  f4 acc = {};
  const float* arow = mean + (size_t)(mt * 16 + lr) * 1024;
  #pragma unroll
  for (int ks = 0; ks < 32; ++ks) {
    const float* ap = arow + ks * 32 + lg * 8;
    h8 a = pack8h(*(const float4*)ap, *(const float4*)(ap + 4));
    h8 b = *(const h8*)(WpreH + (size_t)(nc * 64 + w * 16 + lr) * 1024 + ks * 32 + lg * 8);
    acc = mfma16h(a, b, acc);
  }
  #pragma unroll
  for (int r = 0; r < 4; ++r) {
    int row = mt * 16 + lg * 4 + r, cn = nc * 64 + w * 16 + lr;
    event[(size_t)row * 1024 + cn] = fmaxf(acc[r] + bpre[cn], 0.f);
  }
}

// =================== L5: pos layer1+2 (single-acc K-concat GEMM) + qkv ===================
// grid: [0,1152) pos1 (mb = bid%144, nb = bid/144) | [1152,1728) qkv
// K' = 3072: seg0 eh*wh | seg1 el64*(wh/64) | seg2 (eh/64)*wl64  -- ONE accumulator.
__global__ __launch_bounds__(256, 4) void k_main(
    const int* __restrict__ Ptr, const u16* __restrict__ Ap, const u16* __restrict__ W1B,
    const float* __restrict__ bias1,
    const u16* __restrict__ w2h, const u16* __restrict__ w2hd, const u16* __restrict__ w2l64,
    float* __restrict__ bias_acc,
    const float* __restrict__ event, const int* __restrict__ eidx,
    const u16* __restrict__ WqH, const float* __restrict__ bq,
    const u16* __restrict__ WkH, const float* __restrict__ bk,
    const u16* __restrict__ WvH, const float* __restrict__ bv,
    float* __restrict__ qb, float* __restrict__ kbuf, float* __restrict__ vbuf,
    int pos_on) {
  __shared__ u16 lds[2][2][4096];   // 32 KB: 2 dbuf x {A,B} x 8KB
  int bid = blockIdx.x, tid = threadIdx.x;
  if (bid < 1152) {
    if (!pos_on) return;
    int P = Ptr[0];
    int mb = bid % 144, nb = bid / 144;   // emb-tile sharers 144 apart -> same XCD
    if (mb * 128 >= P) return;
    int w = tid >> 6, lane = tid & 63;
    int lr = lane & 15, lg = lane >> 4;
    int srow[2], scol[2];
    #pragma unroll
    for (int cc = 0; cc < 2; ++cc) {
      int c = w * 2 + cc;
      int d = c * 1024 + lane * 16;
      int b = d ^ (((((d >> 6) & 3)) ^ ((d >> 8) & 3)) << 4);
      srow[cc] = b >> 6;
      scol[cc] = b & 63;
    }
    int rb0 = mb * 128, rb1 = nb * 128;
    auto stage = [&](int buf, int kt2) {
      int seg = kt2 >> 5;
      int kA0 = (seg == 2) ? (kt2 - 64) * 32 : kt2 * 32;   // seg2 re-reads eh
      int kB0 = kt2 * 32;
      #pragma unroll
      for (int cc = 0; cc < 2; ++cc) {
        int c = w * 2 + cc;
        const char* srcA = (const char*)(Ap + (size_t)(rb0 + srow[cc]) * 2048 + kA0) + scol[cc];
        __builtin_amdgcn_global_load_lds(
            (const __attribute__((address_space(1))) char*)srcA,
            (__attribute__((address_space(3))) char*)((char*)&lds[buf][0][0] + c * 1024), 16, 0, 0);
        const char* srcB = (const char*)(W1B + (size_t)(rb1 + srow[cc]) * 3072 + kB0) + scol[cc];
        __builtin_amdgcn_global_load_lds(
            (const __attribute__((address_space(1))) char*)srcB,
            (__attribute__((address_space(3))) char*)((char*)&lds[buf][1][0] + c * 1024), 16, 0, 0);
      }
    };
    stage(0, 0);
    f4 acc[4][4] = {};
    int wm = (w >> 1) * 64, wn = (w & 1) * 64;
    int sl = (lg ^ (lr & 3) ^ ((lr >> 2) & 3)) << 4;   // swizzled 16B slot
    __syncthreads();
    for (int kt = 0; kt < 96; ++kt) {
      int cur = kt & 1;
      if (kt < 95) stage(cur ^ 1, kt + 1);
      h8 ah[4], bh[4];
      #pragma unroll
      for (int mt = 0; mt < 4; ++mt)
        ah[mt] = *(const h8*)((const char*)&lds[cur][0][0] + (wm + mt * 16 + lr) * 64 + sl);
      #pragma unroll
      for (int nt = 0; nt < 4; ++nt)
        bh[nt] = *(const h8*)((const char*)&lds[cur][1][0] + (wn + nt * 16 + lr) * 64 + sl);
      if (kt >= 64) {
        #pragma unroll
        for (int mt = 0; mt < 4; ++mt) ah[mt] = mulInv64(ah[mt]);   // eh/64 (exact)
      }
      #pragma unroll
      for (int mt = 0; mt < 4; ++mt)
        #pragma unroll
        for (int nt = 0; nt < 4; ++nt)
          acc[mt][nt] = mfma16h(ah[mt], bh[nt], acc[mt][nt]);
      __syncthreads();
    }
    // ---- epilogue: layer 2 in two 32-n phases (8 KB zq per wave) ----
    float* zq = (float*)&lds[0][0][0] + w * 2048;
    f4 acc2[4];
    #pragma unroll
    for (int i = 0; i < 4; ++i) acc2[i] = f4{};
    #pragma unroll
    for (int kc = 0; kc < 2; ++kc) {
      #pragma unroll
      for (int mt = 0; mt < 4; ++mt)
        #pragma unroll
        for (int n2 = 0; n2 < 2; ++n2) {
          int nt = kc * 2 + n2;
          #pragma unroll
          for (int r = 0; r < 4; ++r) {
            int pl = mt * 16 + lg * 4 + r;
            int nl = n2 * 16 + lr;              // [0,32)
            float z1 = acc[mt][nt][r] + bias1[nb * 128 + wn + nt * 16 + lr];
            int c4 = nl >> 2;
            zq[pl * 32 + (((c4 ^ (pl & 7)) << 2) | (nl & 3))] = fmaxf(z1, 0.f);
          }
        }
      __syncthreads();
      #pragma unroll
      for (int mt2 = 0; mt2 < 4; ++mt2) {
        int pl = mt2 * 16 + lr;
        int c4a = lg * 2;
        float4 v0 = *(const float4*)(zq + pl * 32 + ((c4a ^ (pl & 7)) << 2));
        float4 v1 = *(const float4*)(zq + pl * 32 + (((c4a + 1) ^ (pl & 7)) << 2));
        h8 ah2, al2, ad2;
        #pragma unroll
        for (int j = 0; j < 4; ++j) {
          h16 h0 = (h16)v0[j];
          ah2[j] = h0; al2[j] = (h16)((v0[j] - (float)h0) * kS); ad2[j] = (h16)((float)h0 * kSInv);
          h16 h1 = (h16)v1[j];
          ah2[4 + j] = h1; al2[4 + j] = (h16)((v1[j] - (float)h1) * kS); ad2[4 + j] = (h16)((float)h1 * kSInv);
        }
        int ng = nb * 128 + wn + kc * 32 + lg * 8;
        h8 b1 = *(const h8*)(w2h + lr * 1024 + ng);
        h8 b2 = *(const h8*)(w2hd + lr * 1024 + ng);
        h8 b3 = *(const h8*)(w2l64 + lr * 1024 + ng);
        acc2[mt2] = mfma16h(ah2, b1, acc2[mt2]);
        acc2[mt2] = mfma16h(al2, b2, acc2[mt2]);
        acc2[mt2] = mfma16h(ad2, b3, acc2[mt2]);
      }
      __syncthreads();
    }
    #pragma unroll
    for (int mt2 = 0; mt2 < 4; ++mt2)
      #pragma unroll
      for (int r = 0; r < 4; ++r) {
        int p = mb * 128 + wm + mt2 * 16 + lg * 4 + r;
        if (p < P)
          atomicAdd(&bias_acc[(size_t)p * 16 + lr], acc2[mt2][r]);
      }
  } else {
    int b2 = bid - 1152;                 // 576 blocks: z, mt, h
    int z = b2 / 192, r2 = b2 % 192, mt = r2 >> 3, h = r2 & 7;
    int w = tid >> 6, lane = tid & 63, lr = lane & 15, lg = lane >> 4;
    const u16* W = (z == 0) ? WqH : (z == 1) ? WkH : WvH;
    const float* bias = (z == 0) ? bq : (z == 1) ? bk : bv;
    float* out = (z == 0) ? qb : (z == 1) ? kbuf : vbuf;
    int row = mt * 16 + lr;
    const float* arow = event + (size_t)eidx[row] * 1024 + h * 128;
    f4 acc[2] = {};
    #pragma unroll
    for (int ks = 0; ks < 4; ++ks) {
      const float* ap = arow + ks * 32 + lg * 8;
      h8 a = pack8h(*(const float4*)ap, *(const float4*)(ap + 4));
      #pragma unroll
      for (int n2 = 0; n2 < 2; ++n2) {
        int nt = w * 2 + n2;
        h8 b = *(const h8*)(W + h * 16384 + (nt * 16 + lr) * 128 + ks * 32 + lg * 8);
        acc[n2] = mfma16h(a, b, acc[n2]);
      }
    }
    #pragma unroll
    for (int n2 = 0; n2 < 2; ++n2)
      #pragma unroll
      for (int r = 0; r < 4; ++r) {
        int rn = mt * 16 + lg * 4 + r, e = (w * 2 + n2) * 16 + lr;
        out[(size_t)rn * 1024 + h * 128 + e] = acc[n2][r] + bias[h * 128 + e];
      }
  }
}

// =================== L6: att (+inline bias finalize) + outx ===================
// grid: [0,6144) att (i = bid>>4, g = bid&15) | [6144,6528) outx
__global__ __launch_bounds__(64) void k_att(const float* __restrict__ q,
                                            const float* __restrict__ kk,
                                            const float* __restrict__ vv,
                                            const float* __restrict__ bias_acc,
                                            const float* __restrict__ bias2,
                                            const int* __restrict__ row_start,
                                            const int* __restrict__ row_len,
                                            const int* __restrict__ row_off,
                                            const float* __restrict__ event,
                                            const int* __restrict__ eidx,
                                            const float* __restrict__ bbox,
                                            float* __restrict__ dout) {
  int bid = blockIdx.x, lane = threadIdx.x;
  if (bid >= 6144) {
    int i = bid - 6144;
    const float* er = event + (size_t)eidx[i] * 1024;
    float* orow = dout + (size_t)i * kOutCols;
    #pragma unroll
    for (int it = 0; it < 4; ++it) {
      int c = lane * 4 + it * 256;
      *(float4*)(orow + c) = *(const float4*)(er + c);
    }
    for (int t = lane; t < 100; t += 64) {
      int qq = t / 25, f = t % 25;
      float x = bbox[i * 2 + (qq >> 1)];
      float ang = 100.f * x * exp2f((float)f * (-13.287712379549449f * 0.04f));
      float sv, cv;
      fsincos(ang, sv, cv);
      orow[2048 + t] = (qq & 1) ? cv : sv;
    }
    return;
  }
  int i = bid >> 4, g = bid & 15;
  int s = row_start[i], L = row_len[i], pb = row_off[i];
  __shared__ float qs[64];
  __shared__ float att[64];
  qs[lane] = q[(size_t)i * 1024 + g * 64 + lane];
  __syncthreads();
  bool valid = lane < L;
  const float* kr = kk + (size_t)(s + (valid ? lane : 0)) * 1024 + g * 64;
  float sc = 0.f;
  #pragma unroll
  for (int dt = 0; dt < 16; ++dt) {
    float4 kv = *(const float4*)(kr + dt * 4);
    sc += qs[dt * 4 + 0] * kv.x + qs[dt * 4 + 1] * kv.y +
          qs[dt * 4 + 2] * kv.z + qs[dt * 4 + 3] * kv.w;
  }
  int pidx = min(pb + lane, kMaxP - 1);
  float pbias = 0.f;
  if (valid) {
    float zs = bias_acc[(size_t)pidx * 16 + g] + bias2[g];
    pbias = logf(fmaxf(zs, 1e-6f));
  }
  sc = valid ? (sc * 0.125f + pbias) : -3.0e38f;
  float mx = sc;
  #pragma unroll
  for (int off = 32; off > 0; off >>= 1) mx = fmaxf(mx, __shfl_xor(mx, off));
  float pe = valid ? __expf(sc - mx) : 0.f;
  float sm = pe;
  #pragma unroll
  for (int off = 32; off > 0; off >>= 1) sm += __shfl_xor(sm, off);
  att[lane] = pe / sm;
  __syncthreads();
  float o = 0.f;
  const float* vb = vv + (size_t)s * 1024 + g * 64 + lane;
  for (int jl = 0; jl < L; ++jl) o += att[jl] * vb[(size_t)jl * 1024];
  dout[(size_t)i * kOutCols + 1024 + g * 64 + lane] = o;
}

// ---------------- FALLBACK fused pos kernel (adapted to kS=64 planes) ----------------
__global__ __launch_bounds__(256) void k_pos(
    const int* __restrict__ Ptr, const int* __restrict__ pair_i,
    const int* __restrict__ pair_j, const float* __restrict__ bbox,
    const u16* __restrict__ W1B, const float* __restrict__ bias1,
    const u16* __restrict__ w2h, const u16* __restrict__ w2l64,
    float* __restrict__ bias_acc) {
  int P = Ptr[0];
  int base0 = blockIdx.x * 64;
  if (base0 >= P) return;
  int w = threadIdx.x >> 6, l = threadIdx.x & 63;
  int lr = l & 15, lg = l >> 4;
  int base = base0 + w * 16;
  int p = base + lr;
  bool valid = p < P;
  int pi = valid ? pair_i[p] : 0;
  int pj = valid ? pair_j[p] : 0;
  double s0 = bbox[pi * 2], e0 = bbox[pi * 2 + 1];
  double s1 = bbox[pj * 2], e1 = bbox[pj * 2 + 1];
  double li = fmax(e0 - s0, 0.1), lj = fmax(e1 - s1, 0.1);
  double dcd = (0.5 * (s0 + e0) - 0.5 * (s1 + e1)) / li;
  double dld = log(lj / li);
  const double kCd = -13.287712379549449 / 256.0;
  double r1  = exp2(kCd);
  double r32 = exp2(kCd * 32.0);
  double pb0 = exp2(kCd * (double)(lg * 8));
  const double INV2PI = 0.15915494309189535;
  const double TWOPI  = 6.283185307179586;
  h8 eh[32], el[32];
  #pragma unroll
  for (int hx = 0; hx < 2; ++hx) {
    double x100 = 100.0 * (hx ? dld : dcd);
    double pch = pb0;
    #pragma unroll
    for (int ksl = 0; ksl < 8; ++ksl) {
      double pp = pch;
      #pragma unroll
      for (int j = 0; j < 8; ++j) {
        double ang = x100 * pp;
        double nn = rint(ang * INV2PI);
        float rf = (float)fma(-nn, TWOPI, ang);
        float sv = __sinf(rf), cv = __cosf(rf);
        h16 sh = (h16)sv, ch = (h16)cv;
        eh[hx * 16 + ksl][j] = sh;
        el[hx * 16 + ksl][j] = (h16)((sv - (float)sh) * kS);
        eh[hx * 16 + 8 + ksl][j] = ch;
        el[hx * 16 + 8 + ksl][j] = (h16)((cv - (float)ch) * kS);
        pp *= r1;
      }
      pch *= r32;
    }
  }
  __shared__ float p1f[4][16 * 64];
  char* myp1 = (char*)p1f[w];
  f4 acc2 = {}, acc2l = {};
  for (int nc = 0; nc < 16; ++nc) {
    f4 accH[4] = {}, accL[4] = {};
    #pragma unroll
    for (int ks = 0; ks < 32; ++ks) {
      #pragma unroll
      for (int nt = 0; nt < 4; ++nt) {
        size_t boff = (size_t)(nc * 64 + nt * 16 + lr) * 3072 + ks * 32 + lg * 8;
        h8 bh = *(const h8*)(W1B + boff);
        h8 bl = *(const h8*)(W1B + boff + 2048);
        accH[nt] = mfma16h(eh[ks], bh, accH[nt]);
        accL[nt] = mfma16h(el[ks], bh, accL[nt]);
        accL[nt] = mfma16h(eh[ks], bl, accL[nt]);
      }
    }
    __syncthreads();
    #pragma unroll
    for (int nt = 0; nt < 4; ++nt)
      #pragma unroll
      for (int r = 0; r < 4; ++r) {
        int m = lg * 4 + r, n = nt * 16 + lr;
        float z1 = accH[nt][r] + accL[nt][r] * kSInv + bias1[nc * 64 + n];
        int byte = ((m * 64 + n) * 4) ^ ((m & 7) << 4);
        *(float*)(myp1 + byte) = fmaxf(z1, 0.f);
      }
    __syncthreads();
    #pragma unroll
    for (int hf = 0; hf < 2; ++hf) {
      int kb = hf * 32 + lg * 8;
      int b0 = ((lr * 64 + kb) * 4) ^ ((lr & 7) << 4);
      int b1 = ((lr * 64 + kb + 4) * 4) ^ ((lr & 7) << 4);
      float4 x0 = *(const float4*)(myp1 + b0);
      float4 x1 = *(const float4*)(myp1 + b1);
      h8 ah, al;
      #pragma unroll
      for (int j = 0; j < 4; ++j) {
        h16 h0 = (h16)x0[j];
        ah[j] = h0; al[j] = (h16)((x0[j] - (float)h0) * kS);
        h16 h1 = (h16)x1[j];
        ah[4 + j] = h1; al[4 + j] = (h16)((x1[j] - (float)h1) * kS);
      }
      h8 bh = *(const h8*)(w2h + lr * 1024 + nc * 64 + kb);
      h8 bl = *(const h8*)(w2l64 + lr * 1024 + nc * 64 + kb);
      acc2  = mfma16h(ah, bh, acc2);
      acc2l = mfma16h(al, bh, acc2l);
      acc2l = mfma16h(ah, bl, acc2l);
    }
  }
  #pragma unroll
  for (int r = 0; r < 4; ++r) {
    int m = lg * 4 + r;
    int pp = base + m;
    if (pp < P)
      bias_acc[(size_t)pp * 16 + lr] = acc2[r] + acc2l[r] * kSInv;
  }
}

extern "C" void kernel_launch(void* const* d_in, const int* in_sizes, int n_in,
                              void* d_out, int out_size, void* d_ws, size_t ws_size,
                              hipStream_t stream) {
  const float* feats = (const float*)d_in[0];
  const int*   gidx  = (const int*)d_in[1];
  const float* cmask = (const float*)d_in[2];
  const int*   eidx  = (const int*)d_in[3];
  const float* bmask = (const float*)d_in[4];
  const float* bbox  = (const float*)d_in[5];
  const float* Wpre  = (const float*)d_in[6];
  const float* bpre  = (const float*)d_in[7];
  const float* Wq    = (const float*)d_in[8];
  const float* bq    = (const float*)d_in[9];
  const float* Wk    = (const float*)d_in[10];
  const float* bk    = (const float*)d_in[11];
  const float* Wv    = (const float*)d_in[12];
  const float* bv    = (const float*)d_in[13];
  const float* Wp1   = (const float*)d_in[14];
  const float* bp1   = (const float*)d_in[15];
  const float* Wp2   = (const float*)d_in[16];
  const float* bp2   = (const float*)d_in[17];

  char* ws = (char*)d_ws;
  size_t off = 0;
  auto alloc = [&](size_t bytes) {
    char* r = ws + off;
    off += (bytes + 255) & ~(size_t)255;
    return r;
  };
  // ---- base allocations ----
  u16* W1B   = (u16*)alloc((size_t)1024 * 3072 * 2);   // [wh | wh/64 | wl*64]
  u16* w2h   = (u16*)alloc((size_t)16384 * 2);
  u16* w2hd  = (u16*)alloc((size_t)16384 * 2);
  u16* w2l64 = (u16*)alloc((size_t)16384 * 2);
  u16* WpreH = (u16*)alloc((size_t)1048576 * 2);
  u16* WqH   = (u16*)alloc((size_t)131072 * 2);
  u16* WkH   = (u16*)alloc((size_t)131072 * 2);
  u16* WvH   = (u16*)alloc((size_t)131072 * 2);
  float* mean  = (float*)alloc((size_t)256 * 1024 * 4);
  float* event = (float*)alloc((size_t)256 * 1024 * 4);
  float* qb    = (float*)alloc((size_t)384 * 1024 * 4);
  float* kb    = (float*)alloc((size_t)384 * 1024 * 4);
  float* vb    = (float*)alloc((size_t)384 * 1024 * 4);
  int* row_start = (int*)alloc(kN * 4);
  int* row_len   = (int*)alloc(kN * 4);
  int* row_off   = (int*)alloc(kN * 4);
  int* Ptr       = (int*)alloc(256);
  int* pair_i    = (int*)alloc((size_t)kMaxP * 4);
  int* pair_j    = (int*)alloc((size_t)kMaxP * 4);
  float* bias_acc = (float*)alloc((size_t)kMaxP * 16 * 4);
  // ---- extended (fast-path) allocations ----
  u16* Ap = (u16*)alloc((size_t)kMaxP * 2048 * 2);     // [eh | el*64]
  bool fast = (off <= ws_size);

  k_ext<<<kN, 64, 0, stream>>>(bmask, row_start, row_len);
  k_scan<<<1, 64, 0, stream>>>(row_len, row_off, Ptr);
  k_big<<<10032, 256, 0, stream>>>(Wp1, W1B, Wp2, w2h, w2hd, w2l64, Wpre, WpreH,
                                   Wq, WqH, Wk, WkH, Wv, WvH,
                                   feats, gidx, cmask, mean, bias_acc,
                                   Ptr, row_start, row_off, bbox, Ap);
  k_egemm<<<256, 256, 0, stream>>>(mean, WpreH, bpre, event);

  if (fast) {
    k_main<<<1728, 256, 0, stream>>>(Ptr, Ap, W1B, bp1, w2h, w2hd, w2l64, bias_acc,
                                     event, eidx, WqH, bq, WkH, bk, WvH, bv,
                                     qb, kb, vb, 1);
  } else {
    k_fill<<<kN, 64, 0, stream>>>(row_start, row_len, row_off, pair_i, pair_j);
    k_pos<<<kMaxP / 64, 256, 0, stream>>>(Ptr, pair_i, pair_j, bbox, W1B, bp1,
                                          w2h, w2l64, bias_acc);
    k_main<<<1728, 256, 0, stream>>>(Ptr, Ap, W1B, bp1, w2h, w2hd, w2l64, bias_acc,
                                     event, eidx, WqH, bq, WkH, bk, WvH, bv,
                                     qb, kb, vb, 0);
  }
  k_att<<<6528, 64, 0, stream>>>(qb, kb, vb, bias_acc, bp2, row_start, row_len, row_off,
                                 event, eidx, bbox, (float*)d_out);
}

// Round 12
// 155.981 us; speedup vs baseline: 1.2272x; 1.2272x over previous
//
#include <hip/hip_runtime.h>
#include <hip/hip_bf16.h>

typedef unsigned short u16;
typedef _Float16 h16;
typedef __attribute__((ext_vector_type(8))) h16 h8;     // 8 x f16 (4 VGPRs)
typedef __attribute__((ext_vector_type(4))) u16 us4;    // 4 x u16
typedef __attribute__((ext_vector_type(4))) float f4;   // MFMA accumulator

#define DEVFN __device__ __forceinline__

constexpr int kN = 384;
constexpr int kL = 64;
constexpr int kMaxP = kN * 48;       // 18432 worst-case in-block pairs
constexpr int kOutCols = 2148;       // 1024 (x) + 1024 (att out) + 100 (e100)
constexpr float kLoScale = 2048.f;   // lo-word scale: keeps residuals f16-normal
constexpr float kLoInv = 1.f / 2048.f;

union HU { h16 h; u16 u; };
DEVFN u16 f2h(float f) { HU c; c.h = (h16)f; return c.u; }
DEVFN float h2f(u16 b) { HU c; c.u = b; return (float)c.h; }

DEVFN f4 mfma16h(h8 a, h8 b, f4 c) {
  return __builtin_amdgcn_mfma_f32_16x16x32_f16(a, b, c, 0, 0, 0);
}

DEVFN h8 pack8h(float4 x0, float4 x1) {
  h8 a;
  a[0] = (h16)x0.x; a[1] = (h16)x0.y; a[2] = (h16)x0.z; a[3] = (h16)x0.w;
  a[4] = (h16)x1.x; a[5] = (h16)x1.y; a[6] = (h16)x1.z; a[7] = (h16)x1.w;
  return a;
}

// f32 sincos with FMA 2-word reduction (non-critical e100 path)
DEVFN void fsincos(float ang, float& s, float& c) {
  float n = rintf(ang * 0.15915494309189535f);
  const float PI2_HI = 6.2831854820251465f;
  const float PI2_LO = -1.7484555e-07f;
  float r = fmaf(-n, PI2_HI, ang);
  r = fmaf(-n, PI2_LO, r);
  s = __sinf(r);
  c = __cosf(r);
}

// =================== L1: per-row block extents ===================
__global__ __launch_bounds__(64) void k_ext(const float* __restrict__ bm,
                                            int* __restrict__ row_start,
                                            int* __restrict__ row_len) {
  int i = blockIdx.x, lane = threadIdx.x;
  int mn = kN, mx = -1;
  #pragma unroll
  for (int jb = 0; jb < kN; jb += 64) {
    float m = bm[(size_t)i * kN + jb + lane];
    if (m > 0.f) { mn = min(mn, jb + lane); mx = max(mx, jb + lane); }
  }
  #pragma unroll
  for (int off = 32; off > 0; off >>= 1) {
    mn = min(mn, __shfl_xor(mn, off));
    mx = max(mx, __shfl_xor(mx, off));
  }
  if (lane == 0) { row_start[i] = mn; row_len[i] = mx - mn + 1; }
}

// =================== L2: exclusive scan of row_len -> row_off, Ptr ===================
__global__ __launch_bounds__(64) void k_scan(const int* __restrict__ row_len,
                                             int* __restrict__ row_off,
                                             int* __restrict__ Ptr) {
  int lane = threadIdx.x;
  int s[6], tot = 0;
  #pragma unroll
  for (int r = 0; r < 6; ++r) { s[r] = tot; tot += row_len[lane * 6 + r]; }
  int run = tot;
  #pragma unroll
  for (int off = 1; off < 64; off <<= 1) {
    int u = __shfl_up(run, off);
    if (lane >= off) run += u;
  }
  int excl = run - tot;
  #pragma unroll
  for (int r = 0; r < 6; ++r) row_off[lane * 6 + r] = excl + s[r];
  if (lane == 63) Ptr[0] = excl + tot;
}

// ---------------- fill flat pair list (fallback path only) ----------------
__global__ __launch_bounds__(64) void k_fill(const int* __restrict__ row_start,
                                             const int* __restrict__ row_len,
                                             const int* __restrict__ row_off,
                                             int* __restrict__ pair_i,
                                             int* __restrict__ pair_j) {
  int i = blockIdx.x, lane = threadIdx.x;
  int s = row_start[i], len = row_len[i], off = row_off[i];
  if (lane < len) { pair_i[off + lane] = i; pair_j[off + lane] = s + lane; }
}

// =================== L3: cvt | mean | zero | emb (all independent, co-resident) =======
// grid: [0,512) cvt | [512,768) mean | [768,816) zero bias_acc | [816,10032) emb
__global__ __launch_bounds__(256) void k_big(
    const float* __restrict__ Wp1, u16* __restrict__ W1H, u16* __restrict__ W1L,
    const float* __restrict__ Wp2, u16* __restrict__ W2H, u16* __restrict__ W2L,
    const float* __restrict__ Wpre, u16* __restrict__ WpreH,
    const float* __restrict__ Wq, u16* __restrict__ WqH,
    const float* __restrict__ Wk, u16* __restrict__ WkH,
    const float* __restrict__ Wv, u16* __restrict__ WvH,
    const float* __restrict__ feats, const int* __restrict__ gidx,
    const float* __restrict__ cmask, float* __restrict__ mean,
    float* __restrict__ bias_acc,
    const int* __restrict__ Ptr, const int* __restrict__ row_start,
    const int* __restrict__ row_off, const float* __restrict__ bbox,
    u16* __restrict__ ehi, u16* __restrict__ elo) {
  int bid = blockIdx.x, t = threadIdx.x;
  if (bid < 512) {
    const int nW1 = 1048576, nW2 = 16384, nPre = 1048576, nQ = 131072;
    const int tot = nW1 + nW2 + nPre + 3 * nQ;
    for (int i = bid * 256 + t; i < tot; i += 512 * 256) {
      if (i < nW1) {
        float x = Wp1[i]; u16 h = f2h(x);
        W1H[i] = h; W1L[i] = f2h((x - h2f(h)) * kLoScale);
      } else if (i < nW1 + nW2) {
        int j = i - nW1; float x = Wp2[j]; u16 h = f2h(x);
        W2H[j] = h; W2L[j] = f2h((x - h2f(h)) * kLoScale);
      } else if (i < nW1 + nW2 + nPre) {
        int j = i - nW1 - nW2; WpreH[j] = f2h(Wpre[j]);
      } else {
        int j = i - nW1 - nW2 - nPre;
        int a = j / nQ, r = j % nQ;
        const float* s = (a == 0) ? Wq : (a == 1) ? Wk : Wv;
        u16* d = (a == 0) ? WqH : (a == 1) ? WkH : WvH;
        d[r] = f2h(s[r]);
      }
    }
  } else if (bid < 768) {
    int e = bid - 512;
    float4 a = {0.f, 0.f, 0.f, 0.f};
    float ms = 0.f;
    for (int l = 0; l < kL; ++l) {
      float m = cmask[e * kL + l];
      ms += m;
      if (m > 0.f) {
        float4 v = *(const float4*)(feats + (size_t)gidx[e * kL + l] * 1024 + t * 4);
        a.x += v.x; a.y += v.y; a.z += v.z; a.w += v.w;
      }
    }
    float inv = 1.f / (ms + 1e-5f);
    float4 o = {a.x * inv, a.y * inv, a.z * inv, a.w * inv};
    *(float4*)(mean + (size_t)e * 1024 + t * 4) = o;
  } else if (bid < 816) {
    float4 z = {0.f, 0.f, 0.f, 0.f};
    for (int i4 = (bid - 768) * 256 + t; i4 < kMaxP * 16 / 4; i4 += 48 * 256)
      *(float4*)(bias_acc + (size_t)i4 * 4) = z;
  } else {
    int eb = bid - 816;                  // emb: 2 pairs per block
    int P = Ptr[0];
    int Pc = (P + 127) & ~127;
    if (eb * 2 >= Pc) return;
    __shared__ double As[16], Bs[16];
    __shared__ int roff[384], rstart[384];
    const double kCd = -13.287712379549449 / 256.0;
    if (t < 16) As[t] = exp2(kCd * (double)(t * 16));
    else if (t < 32) Bs[t - 16] = exp2(kCd * (double)(t - 16));
    for (int k = t; k < 384; k += 256) { roff[k] = row_off[k]; rstart[k] = row_start[k]; }
    __syncthreads();
    int p = eb * 2 + (t >> 7);
    int u = t & 127;
    int hseg = u >> 6;                   // 0: dc half, 1: dl half
    int f0 = (u & 63) * 4;               // 4 consecutive freqs per thread
    size_t ob = (size_t)p * 1024 + hseg * 512 + f0;
    if (p >= P) {
      us4 z = {0, 0, 0, 0};
      *(us4*)(ehi + ob) = z; *(us4*)(ehi + ob + 256) = z;
      *(us4*)(elo + ob) = z; *(us4*)(elo + ob + 256) = z;
      return;
    }
    int lo = 0, hi = 383;
    while (lo < hi) { int md = (lo + hi + 1) >> 1; if (roff[md] <= p) lo = md; else hi = md - 1; }
    int pi = lo, pj = rstart[lo] + (p - roff[lo]);
    double s0 = bbox[pi * 2], e0 = bbox[pi * 2 + 1];
    double s1 = bbox[pj * 2], e1 = bbox[pj * 2 + 1];
    double li = fmax(e0 - s0, 0.1), lj = fmax(e1 - s1, 0.1);
    double x = hseg ? log(lj / li) : (0.5 * (s0 + e0) - 0.5 * (s1 + e1)) / li;
    double x100 = 100.0 * x;
    const double INV2PI = 0.15915494309189535;
    const double TWOPI  = 6.283185307179586;
    us4 sh_, sl_, ch_, cl_;
    #pragma unroll
    for (int j = 0; j < 4; ++j) {
      int f = f0 + j;
      double ang = x100 * (As[f >> 4] * Bs[f & 15]);
      double nn = rint(ang * INV2PI);
      float rf = (float)fma(-nn, TWOPI, ang);
      float sv = __sinf(rf), cv = __cosf(rf);
      u16 hs = f2h(sv); sh_[j] = hs; sl_[j] = f2h((sv - h2f(hs)) * kLoScale);
      u16 hc = f2h(cv); ch_[j] = hc; cl_[j] = f2h((cv - h2f(hc)) * kLoScale);
    }
    *(us4*)(ehi + ob) = sh_; *(us4*)(ehi + ob + 256) = ch_;
    *(us4*)(elo + ob) = sl_; *(us4*)(elo + ob + 256) = cl_;
  }
}

// =================== L4: event = relu(mean @ Wpre^T + bpre) ===================
__global__ __launch_bounds__(256) void k_egemm(const float* __restrict__ mean,
                                               const u16* __restrict__ WpreH,
                                               const float* __restrict__ bpre,
                                               float* __restrict__ event) {
  int mt = blockIdx.x >> 4, nc = blockIdx.x & 15;
  int t = threadIdx.x;
  int w = t >> 6, lane = t & 63, lr = lane & 15, lg = lane >> 4;
  f4 acc = {};
  const float* arow = mean + (size_t)(mt * 16 + lr) * 1024;
  #pragma unroll
  for (int ks = 0; ks < 32; ++ks) {
    const float* ap = arow + ks * 32 + lg * 8;
    h8 a = pack8h(*(const float4*)ap, *(const float4*)(ap + 4));
    h8 b = *(const h8*)(WpreH + (size_t)(nc * 64 + w * 16 + lr) * 1024 + ks * 32 + lg * 8);
    acc = mfma16h(a, b, acc);
  }
  #pragma unroll
  for (int r = 0; r < 4; ++r) {
    int row = mt * 16 + lg * 4 + r, cn = nc * 64 + w * 16 + lr;
    event[(size_t)row * 1024 + cn] = fmaxf(acc[r] + bpre[cn], 0.f);
  }
}

// =================== L5: pos layer1+2 GEMM (round-10 structure) + qkv ===================
// grid: [0,1152) pos1 (mb = bid%144, nb = bid/144 -- emb-tile sharers land same-XCD)
//       [1152,1728) qkv (z,mt,h; 4 waves = 8 nt)
__global__ __launch_bounds__(256, 2) void k_main(
    const int* __restrict__ Ptr, const u16* __restrict__ ehi, const u16* __restrict__ elo,
    const u16* __restrict__ W1h, const u16* __restrict__ W1l, const float* __restrict__ bias1,
    const u16* __restrict__ W2h, const u16* __restrict__ W2l, float* __restrict__ bias_acc,
    const float* __restrict__ event, const int* __restrict__ eidx,
    const u16* __restrict__ WqH, const float* __restrict__ bq,
    const u16* __restrict__ WkH, const float* __restrict__ bk,
    const u16* __restrict__ WvH, const float* __restrict__ bv,
    float* __restrict__ qb, float* __restrict__ kbuf, float* __restrict__ vbuf,
    int pos_on) {
  __shared__ u16 lds[2][4][4096];
  int bid = blockIdx.x, tid = threadIdx.x;
  if (bid < 1152) {
    if (!pos_on) return;
    int P = Ptr[0];
    int mb = bid % 144, nb = bid / 144;  // 8 sharers of emb tile mb are 144 apart -> same XCD
    if (mb * 128 >= P) return;
    int w = tid >> 6, lane = tid & 63;
    int lr = lane & 15, lg = lane >> 4;
    int srow[2], scol[2];
    #pragma unroll
    for (int cc = 0; cc < 2; ++cc) {
      int c = w * 2 + cc;
      int d = c * 1024 + lane * 16;
      int b = d ^ (((((d >> 6) & 3)) ^ ((d >> 8) & 3)) << 4);
      srow[cc] = b >> 6;
      scol[cc] = b & 63;
    }
    const u16* planes[4] = {ehi, elo, W1h, W1l};
    int rb0 = mb * 128, rb1 = nb * 128;
    auto stage = [&](int buf, int k0) {
      #pragma unroll
      for (int t = 0; t < 4; ++t) {
        int rbase = (t < 2) ? rb0 : rb1;
        #pragma unroll
        for (int cc = 0; cc < 2; ++cc) {
          int c = w * 2 + cc;
          const char* src = (const char*)(planes[t] + (size_t)(rbase + srow[cc]) * 1024 + k0) + scol[cc];
          char* dst = (char*)&lds[buf][t][0] + c * 1024;
          __builtin_amdgcn_global_load_lds(
              (const __attribute__((address_space(1))) char*)src,
              (__attribute__((address_space(3))) char*)dst, 16, 0, 0);
        }
      }
    };
    stage(0, 0);
    f4 aH[4][4] = {}, aL[4][4] = {};
    int wm = (w >> 1) * 64, wn = (w & 1) * 64;
    int sl = (lg ^ (lr & 3) ^ ((lr >> 2) & 3)) << 4;   // swizzled 16B slot
    __syncthreads();
    for (int kt = 0; kt < 32; ++kt) {
      int cur = kt & 1;
      if (kt < 31) stage(cur ^ 1, (kt + 1) * 32);
      h8 ah[4], al[4], bh[4], bl[4];
      #pragma unroll
      for (int mt = 0; mt < 4; ++mt) {
        int ad = (wm + mt * 16 + lr) * 64 + sl;
        ah[mt] = *(const h8*)((const char*)&lds[cur][0][0] + ad);
        al[mt] = *(const h8*)((const char*)&lds[cur][1][0] + ad);
      }
      #pragma unroll
      for (int nt = 0; nt < 4; ++nt) {
        int ad = (wn + nt * 16 + lr) * 64 + sl;
        bh[nt] = *(const h8*)((const char*)&lds[cur][2][0] + ad);
        bl[nt] = *(const h8*)((const char*)&lds[cur][3][0] + ad);
      }
      #pragma unroll
      for (int mt = 0; mt < 4; ++mt)
        #pragma unroll
        for (int nt = 0; nt < 4; ++nt) {
          aH[mt][nt] = mfma16h(ah[mt], bh[nt], aH[mt][nt]);
          aL[mt][nt] = mfma16h(al[mt], bh[nt], aL[mt][nt]);
          aL[mt][nt] = mfma16h(ah[mt], bl[nt], aL[mt][nt]);
        }
      __syncthreads();
    }
    // ---- epilogue: z1 quadrant -> LDS (swizzled) ----
    float* zq = (float*)&lds[0][0][0] + w * 4096;   // 16KB per wave
    #pragma unroll
    for (int mt = 0; mt < 4; ++mt)
      #pragma unroll
      for (int nt = 0; nt < 4; ++nt)
        #pragma unroll
        for (int r = 0; r < 4; ++r) {
          int pl = mt * 16 + lg * 4 + r;
          int nl = nt * 16 + lr;
          float z1 = aH[mt][nt][r] + aL[mt][nt][r] * kLoInv + bias1[nb * 128 + wn + nl];
          zq[pl * 64 + (nl ^ ((pl & 7) << 3))] = fmaxf(z1, 0.f);
        }
    __syncthreads();
    // ---- layer 2: z2 partial = relu(z1) @ W2^T over this wave's 64 n ----
    f4 c2h[4], c2l[4];
    #pragma unroll
    for (int i = 0; i < 4; ++i) { c2h[i] = f4{}; c2l[i] = f4{}; }
    #pragma unroll
    for (int mt2 = 0; mt2 < 4; ++mt2) {
      #pragma unroll
      for (int kc = 0; kc < 2; ++kc) {
        int pl = mt2 * 16 + lr;
        int n0 = kc * 32 + lg * 8;
        const float* rp = zq + pl * 64 + (n0 ^ ((pl & 7) << 3));
        float4 v0 = *(const float4*)rp;
        float4 v1 = *(const float4*)(rp + 4);
        h8 ah2, al2;
        #pragma unroll
        for (int j = 0; j < 4; ++j) {
          h16 h0 = (h16)v0[j]; ah2[j] = h0;     al2[j] = (h16)((v0[j] - (float)h0) * kLoScale);
          h16 h1 = (h16)v1[j]; ah2[4 + j] = h1; al2[4 + j] = (h16)((v1[j] - (float)h1) * kLoScale);
        }
        int ng = nb * 128 + wn + n0;
        h8 bh2 = *(const h8*)(W2h + lr * 1024 + ng);
        h8 bl2 = *(const h8*)(W2l + lr * 1024 + ng);
        c2h[mt2] = mfma16h(ah2, bh2, c2h[mt2]);
        c2l[mt2] = mfma16h(al2, bh2, c2l[mt2]);
        c2l[mt2] = mfma16h(ah2, bl2, c2l[mt2]);
      }
    }
    #pragma unroll
    for (int mt2 = 0; mt2 < 4; ++mt2)
      #pragma unroll
      for (int r = 0; r < 4; ++r) {
        int p = mb * 128 + wm + mt2 * 16 + lg * 4 + r;
        if (p < P)
          atomicAdd(&bias_acc[(size_t)p * 16 + lr], c2h[mt2][r] + c2l[mt2][r] * kLoInv);
      }
  } else {
    int b2 = bid - 1152;                 // 576 blocks: z, mt, h
    int z = b2 / 192, r2 = b2 % 192, mt = r2 >> 3, h = r2 & 7;
    int w = tid >> 6, lane = tid & 63, lr = lane & 15, lg = lane >> 4;
    const u16* W = (z == 0) ? WqH : (z == 1) ? WkH : WvH;
    const float* bias = (z == 0) ? bq : (z == 1) ? bk : bv;
    float* out = (z == 0) ? qb : (z == 1) ? kbuf : vbuf;
    int row = mt * 16 + lr;
    const float* arow = event + (size_t)eidx[row] * 1024 + h * 128;
    f4 acc[2] = {};
    #pragma unroll
    for (int ks = 0; ks < 4; ++ks) {
      const float* ap = arow + ks * 32 + lg * 8;
      h8 a = pack8h(*(const float4*)ap, *(const float4*)(ap + 4));
      #pragma unroll
      for (int n2 = 0; n2 < 2; ++n2) {
        int nt = w * 2 + n2;
        h8 b = *(const h8*)(W + h * 16384 + (nt * 16 + lr) * 128 + ks * 32 + lg * 8);
        acc[n2] = mfma16h(a, b, acc[n2]);
      }
    }
    #pragma unroll
    for (int n2 = 0; n2 < 2; ++n2)
      #pragma unroll
      for (int r = 0; r < 4; ++r) {
        int rn = mt * 16 + lg * 4 + r, e = (w * 2 + n2) * 16 + lr;
        out[(size_t)rn * 1024 + h * 128 + e] = acc[n2][r] + bias[h * 128 + e];
      }
  }
}

// =================== L6: att (+inline bias finalize) + outx ===================
// grid: [0,6144) att (i = bid>>4, g = bid&15) | [6144,6528) outx
__global__ __launch_bounds__(64) void k_att(const float* __restrict__ q,
                                            const float* __restrict__ kk,
                                            const float* __restrict__ vv,
                                            const float* __restrict__ bias_acc,
                                            const float* __restrict__ bias2,
                                            const int* __restrict__ row_start,
                                            const int* __restrict__ row_len,
                                            const int* __restrict__ row_off,
                                            const float* __restrict__ event,
                                            const int* __restrict__ eidx,
                                            const float* __restrict__ bbox,
                                            float* __restrict__ dout) {
  int bid = blockIdx.x, lane = threadIdx.x;
  if (bid >= 6144) {
    int i = bid - 6144;
    const float* er = event + (size_t)eidx[i] * 1024;
    float* orow = dout + (size_t)i * kOutCols;
    #pragma unroll
    for (int it = 0; it < 4; ++it) {
      int c = lane * 4 + it * 256;
      *(float4*)(orow + c) = *(const float4*)(er + c);
    }
    for (int t = lane; t < 100; t += 64) {
      int qq = t / 25, f = t % 25;
      float x = bbox[i * 2 + (qq >> 1)];
      float ang = 100.f * x * exp2f((float)f * (-13.287712379549449f * 0.04f));
      float sv, cv;
      fsincos(ang, sv, cv);
      orow[2048 + t] = (qq & 1) ? cv : sv;
    }
    return;
  }
  int i = bid >> 4, g = bid & 15;
  int s = row_start[i], L = row_len[i], pb = row_off[i];
  __shared__ float qs[64];
  __shared__ float att[64];
  qs[lane] = q[(size_t)i * 1024 + g * 64 + lane];
  __syncthreads();
  bool valid = lane < L;
  const float* kr = kk + (size_t)(s + (valid ? lane : 0)) * 1024 + g * 64;
  float sc = 0.f;
  #pragma unroll
  for (int dt = 0; dt < 16; ++dt) {
    float4 kv = *(const float4*)(kr + dt * 4);
    sc += qs[dt * 4 + 0] * kv.x + qs[dt * 4 + 1] * kv.y +
          qs[dt * 4 + 2] * kv.z + qs[dt * 4 + 3] * kv.w;
  }
  int pidx = min(pb + lane, kMaxP - 1);
  float pbias = 0.f;
  if (valid) {
    float zs = bias_acc[(size_t)pidx * 16 + g] + bias2[g];
    pbias = logf(fmaxf(zs, 1e-6f));
  }
  sc = valid ? (sc * 0.125f + pbias) : -3.0e38f;
  float mx = sc;
  #pragma unroll
  for (int off = 32; off > 0; off >>= 1) mx = fmaxf(mx, __shfl_xor(mx, off));
  float pe = valid ? __expf(sc - mx) : 0.f;
  float sm = pe;
  #pragma unroll
  for (int off = 32; off > 0; off >>= 1) sm += __shfl_xor(sm, off);
  att[lane] = pe / sm;
  __syncthreads();
  float o = 0.f;
  const float* vb = vv + (size_t)s * 1024 + g * 64 + lane;
  for (int jl = 0; jl < L; ++jl) o += att[jl] * vb[(size_t)jl * 1024];
  dout[(size_t)i * kOutCols + 1024 + g * 64 + lane] = o;
}

// ---------------- FALLBACK fused pos kernel: writes raw z2 sum into bias_acc ----------
__global__ __launch_bounds__(256) void k_pos(
    const int* __restrict__ Ptr, const int* __restrict__ pair_i,
    const int* __restrict__ pair_j, const float* __restrict__ bbox,
    const u16* __restrict__ W1h, const u16* __restrict__ W1l,
    const float* __restrict__ bias1,
    const u16* __restrict__ W2h, const u16* __restrict__ W2l,
    float* __restrict__ bias_acc) {
  int P = Ptr[0];
  int base0 = blockIdx.x * 64;
  if (base0 >= P) return;
  int w = threadIdx.x >> 6, l = threadIdx.x & 63;
  int lr = l & 15, lg = l >> 4;
  int base = base0 + w * 16;
  int p = base + lr;
  bool valid = p < P;
  int pi = valid ? pair_i[p] : 0;
  int pj = valid ? pair_j[p] : 0;
  double s0 = bbox[pi * 2], e0 = bbox[pi * 2 + 1];
  double s1 = bbox[pj * 2], e1 = bbox[pj * 2 + 1];
  double li = fmax(e0 - s0, 0.1), lj = fmax(e1 - s1, 0.1);
  double dcd = (0.5 * (s0 + e0) - 0.5 * (s1 + e1)) / li;
  double dld = log(lj / li);
  const double kCd = -13.287712379549449 / 256.0;
  double r1  = exp2(kCd);
  double r32 = exp2(kCd * 32.0);
  double pb0 = exp2(kCd * (double)(lg * 8));
  const double INV2PI = 0.15915494309189535;
  const double TWOPI  = 6.283185307179586;
  h8 eh[32], el[32];
  #pragma unroll
  for (int hx = 0; hx < 2; ++hx) {
    double x100 = 100.0 * (hx ? dld : dcd);
    double pch = pb0;
    #pragma unroll
    for (int ksl = 0; ksl < 8; ++ksl) {
      double pp = pch;
      #pragma unroll
      for (int j = 0; j < 8; ++j) {
        double ang = x100 * pp;
        double nn = rint(ang * INV2PI);
        float rf = (float)fma(-nn, TWOPI, ang);
        float sv = __sinf(rf), cv = __cosf(rf);
        h16 sh = (h16)sv, ch = (h16)cv;
        eh[hx * 16 + ksl][j] = sh;
        el[hx * 16 + ksl][j] = (h16)((sv - (float)sh) * kLoScale);
        eh[hx * 16 + 8 + ksl][j] = ch;
        el[hx * 16 + 8 + ksl][j] = (h16)((cv - (float)ch) * kLoScale);
        pp *= r1;
      }
      pch *= r32;
    }
  }
  __shared__ float p1f[4][16 * 64];
  char* myp1 = (char*)p1f[w];
  f4 acc2 = {}, acc2l = {};
  for (int nc = 0; nc < 16; ++nc) {
    f4 accH[4] = {}, accL[4] = {};
    #pragma unroll
    for (int ks = 0; ks < 32; ++ks) {
      #pragma unroll
      for (int nt = 0; nt < 4; ++nt) {
        size_t boff = (size_t)(nc * 64 + nt * 16 + lr) * 1024 + ks * 32 + lg * 8;
        h8 bh = *(const h8*)(W1h + boff);
        h8 bl = *(const h8*)(W1l + boff);
        accH[nt] = mfma16h(eh[ks], bh, accH[nt]);
        accL[nt] = mfma16h(el[ks], bh, accL[nt]);
        accL[nt] = mfma16h(eh[ks], bl, accL[nt]);
      }
    }
    __syncthreads();
    #pragma unroll
    for (int nt = 0; nt < 4; ++nt)
      #pragma unroll
      for (int r = 0; r < 4; ++r) {
        int m = lg * 4 + r, n = nt * 16 + lr;
        float z1 = accH[nt][r] + accL[nt][r] * kLoInv + bias1[nc * 64 + n];
        int byte = ((m * 64 + n) * 4) ^ ((m & 7) << 4);
        *(float*)(myp1 + byte) = fmaxf(z1, 0.f);
      }
    __syncthreads();
    #pragma unroll
    for (int hf = 0; hf < 2; ++hf) {
      int kb = hf * 32 + lg * 8;
      int b0 = ((lr * 64 + kb) * 4) ^ ((lr & 7) << 4);
      int b1 = ((lr * 64 + kb + 4) * 4) ^ ((lr & 7) << 4);
      float4 x0 = *(const float4*)(myp1 + b0);
      float4 x1 = *(const float4*)(myp1 + b1);
      h8 ah, al;
      #pragma unroll
      for (int j = 0; j < 4; ++j) {
        h16 h0 = (h16)x0[j];
        ah[j] = h0; al[j] = (h16)((x0[j] - (float)h0) * kLoScale);
        h16 h1 = (h16)x1[j];
        ah[4 + j] = h1; al[4 + j] = (h16)((x1[j] - (float)h1) * kLoScale);
      }
      h8 bh = *(const h8*)(W2h + lr * 1024 + nc * 64 + kb);
      h8 bl = *(const h8*)(W2l + lr * 1024 + nc * 64 + kb);
      acc2  = mfma16h(ah, bh, acc2);
      acc2l = mfma16h(al, bh, acc2l);
      acc2l = mfma16h(ah, bl, acc2l);
    }
  }
  #pragma unroll
  for (int r = 0; r < 4; ++r) {
    int m = lg * 4 + r;
    int pp = base + m;
    if (pp < P)
      bias_acc[(size_t)pp * 16 + lr] = acc2[r] + acc2l[r] * kLoInv;
  }
}

extern "C" void kernel_launch(void* const* d_in, const int* in_sizes, int n_in,
                              void* d_out, int out_size, void* d_ws, size_t ws_size,
                              hipStream_t stream) {
  const float* feats = (const float*)d_in[0];
  const int*   gidx  = (const int*)d_in[1];
  const float* cmask = (const float*)d_in[2];
  const int*   eidx  = (const int*)d_in[3];
  const float* bmask = (const float*)d_in[4];
  const float* bbox  = (const float*)d_in[5];
  const float* Wpre  = (const float*)d_in[6];
  const float* bpre  = (const float*)d_in[7];
  const float* Wq    = (const float*)d_in[8];
  const float* bq    = (const float*)d_in[9];
  const float* Wk    = (const float*)d_in[10];
  const float* bk    = (const float*)d_in[11];
  const float* Wv    = (const float*)d_in[12];
  const float* bv    = (const float*)d_in[13];
  const float* Wp1   = (const float*)d_in[14];
  const float* bp1   = (const float*)d_in[15];
  const float* Wp2   = (const float*)d_in[16];
  const float* bp2   = (const float*)d_in[17];

  char* ws = (char*)d_ws;
  size_t off = 0;
  auto alloc = [&](size_t bytes) {
    char* r = ws + off;
    off += (bytes + 255) & ~(size_t)255;
    return r;
  };
  // ---- base allocations ----
  u16* W1H   = (u16*)alloc((size_t)1048576 * 2);
  u16* W1L   = (u16*)alloc((size_t)1048576 * 2);
  u16* W2H   = (u16*)alloc((size_t)16384 * 2);
  u16* W2L   = (u16*)alloc((size_t)16384 * 2);
  u16* WpreH = (u16*)alloc((size_t)1048576 * 2);
  u16* WqH   = (u16*)alloc((size_t)131072 * 2);
  u16* WkH   = (u16*)alloc((size_t)131072 * 2);
  u16* WvH   = (u16*)alloc((size_t)131072 * 2);
  float* mean  = (float*)alloc((size_t)256 * 1024 * 4);
  float* event = (float*)alloc((size_t)256 * 1024 * 4);
  float* qb    = (float*)alloc((size_t)384 * 1024 * 4);
  float* kb    = (float*)alloc((size_t)384 * 1024 * 4);
  float* vb    = (float*)alloc((size_t)384 * 1024 * 4);
  int* row_start = (int*)alloc(kN * 4);
  int* row_len   = (int*)alloc(kN * 4);
  int* row_off   = (int*)alloc(kN * 4);
  int* Ptr       = (int*)alloc(256);
  int* pair_i    = (int*)alloc((size_t)kMaxP * 4);
  int* pair_j    = (int*)alloc((size_t)kMaxP * 4);
  float* bias_acc = (float*)alloc((size_t)kMaxP * 16 * 4);
  // ---- extended (fast-path) allocations ----
  u16* ehi      = (u16*)alloc((size_t)kMaxP * 1024 * 2);
  u16* elo      = (u16*)alloc((size_t)kMaxP * 1024 * 2);
  bool fast = (off <= ws_size);

  k_ext<<<kN, 64, 0, stream>>>(bmask, row_start, row_len);
  k_scan<<<1, 64, 0, stream>>>(row_len, row_off, Ptr);
  k_big<<<10032, 256, 0, stream>>>(Wp1, W1H, W1L, Wp2, W2H, W2L, Wpre, WpreH,
                                   Wq, WqH, Wk, WkH, Wv, WvH,
                                   feats, gidx, cmask, mean, bias_acc,
                                   Ptr, row_start, row_off, bbox, ehi, elo);
  k_egemm<<<256, 256, 0, stream>>>(mean, WpreH, bpre, event);

  if (fast) {
    k_main<<<1728, 256, 0, stream>>>(Ptr, ehi, elo, W1H, W1L, bp1, W2H, W2L, bias_acc,
                                     event, eidx, WqH, bq, WkH, bk, WvH, bv,
                                     qb, kb, vb, 1);
  } else {
    k_fill<<<kN, 64, 0, stream>>>(row_start, row_len, row_off, pair_i, pair_j);
    k_pos<<<kMaxP / 64, 256, 0, stream>>>(Ptr, pair_i, pair_j, bbox, W1H, W1L, bp1,
                                          W2H, W2L, bias_acc);
    k_main<<<1728, 256, 0, stream>>>(Ptr, ehi, elo, W1H, W1L, bp1, W2H, W2L, bias_acc,
                                     event, eidx, WqH, bq, WkH, bk, WvH, bv,
                                     qb, kb, vb, 0);
  }
  k_att<<<6528, 64, 0, stream>>>(qb, kb, vb, bias_acc, bp2, row_start, row_len, row_off,
                                 event, eidx, bbox, (float*)d_out);
}

// Round 13
// 153.812 us; speedup vs baseline: 1.2445x; 1.0141x over previous
//
#include <hip/hip_runtime.h>
#include <hip/hip_bf16.h>

typedef unsigned short u16;
typedef _Float16 h16;
typedef __attribute__((ext_vector_type(8))) h16 h8;     // 8 x f16 (4 VGPRs)
typedef __attribute__((ext_vector_type(4))) u16 us4;    // 4 x u16
typedef __attribute__((ext_vector_type(4))) float f4;   // MFMA accumulator

#define DEVFN __device__ __forceinline__

constexpr int kN = 384;
constexpr int kL = 64;
constexpr int kMaxP = kN * 48;       // 18432 worst-case in-block pairs
constexpr int kOutCols = 2148;       // 1024 (x) + 1024 (att out) + 100 (e100)
constexpr float kLoScale = 2048.f;   // lo-word scale: keeps residuals f16-normal
constexpr float kLoInv = 1.f / 2048.f;

union HU { h16 h; u16 u; };
DEVFN u16 f2h(float f) { HU c; c.h = (h16)f; return c.u; }
DEVFN float h2f(u16 b) { HU c; c.u = b; return (float)c.h; }

DEVFN f4 mfma16h(h8 a, h8 b, f4 c) {
  return __builtin_amdgcn_mfma_f32_16x16x32_f16(a, b, c, 0, 0, 0);
}

DEVFN h8 pack8h(float4 x0, float4 x1) {
  h8 a;
  a[0] = (h16)x0.x; a[1] = (h16)x0.y; a[2] = (h16)x0.z; a[3] = (h16)x0.w;
  a[4] = (h16)x1.x; a[5] = (h16)x1.y; a[6] = (h16)x1.z; a[7] = (h16)x1.w;
  return a;
}

// f32 sincos with FMA 2-word reduction (non-critical e100 path)
DEVFN void fsincos(float ang, float& s, float& c) {
  float n = rintf(ang * 0.15915494309189535f);
  const float PI2_HI = 6.2831854820251465f;
  const float PI2_LO = -1.7484555e-07f;
  float r = fmaf(-n, PI2_HI, ang);
  r = fmaf(-n, PI2_LO, r);
  s = __sinf(r);
  c = __cosf(r);
}

// =================== P1: ext | mean | zero (all independent) ===================
// grid: [0,96) extents (4 rows/block) | [96,352) mean | [352,400) zero bias_acc
__global__ __launch_bounds__(256) void k_pre(
    const float* __restrict__ bm, int* __restrict__ row_start, int* __restrict__ row_len,
    const float* __restrict__ feats, const int* __restrict__ gidx,
    const float* __restrict__ cmask, float* __restrict__ mean,
    float* __restrict__ bias_acc) {
  int bid = blockIdx.x, t = threadIdx.x;
  if (bid < 96) {
    int w = t >> 6, lane = t & 63;
    int i = bid * 4 + w;
    int mn = kN, mx = -1;
    #pragma unroll
    for (int jb = 0; jb < kN; jb += 64) {
      float m = bm[(size_t)i * kN + jb + lane];
      if (m > 0.f) { mn = min(mn, jb + lane); mx = max(mx, jb + lane); }
    }
    #pragma unroll
    for (int off = 32; off > 0; off >>= 1) {
      mn = min(mn, __shfl_xor(mn, off));
      mx = max(mx, __shfl_xor(mx, off));
    }
    if (lane == 0) { row_start[i] = mn; row_len[i] = mx - mn + 1; }
  } else if (bid < 352) {
    int e = bid - 96;
    float4 a = {0.f, 0.f, 0.f, 0.f};
    float ms = 0.f;
    for (int l = 0; l < kL; ++l) {
      float m = cmask[e * kL + l];
      ms += m;
      if (m > 0.f) {
        float4 v = *(const float4*)(feats + (size_t)gidx[e * kL + l] * 1024 + t * 4);
        a.x += v.x; a.y += v.y; a.z += v.z; a.w += v.w;
      }
    }
    float inv = 1.f / (ms + 1e-5f);
    float4 o = {a.x * inv, a.y * inv, a.z * inv, a.w * inv};
    *(float4*)(mean + (size_t)e * 1024 + t * 4) = o;
  } else {
    float4 z = {0.f, 0.f, 0.f, 0.f};
    for (int i4 = (bid - 352) * 256 + t; i4 < kMaxP * 16 / 4; i4 += 48 * 256)
      *(float4*)(bias_acc + (size_t)i4 * 4) = z;
  }
}

// =================== P2: exclusive scan of row_len -> row_off, Ptr ===================
__global__ __launch_bounds__(64) void k_scan(const int* __restrict__ row_len,
                                             int* __restrict__ row_off,
                                             int* __restrict__ Ptr) {
  int lane = threadIdx.x;
  int s[6], tot = 0;
  #pragma unroll
  for (int r = 0; r < 6; ++r) { s[r] = tot; tot += row_len[lane * 6 + r]; }
  int run = tot;
  #pragma unroll
  for (int off = 1; off < 64; off <<= 1) {
    int u = __shfl_up(run, off);
    if (lane >= off) run += u;
  }
  int excl = run - tot;
  #pragma unroll
  for (int r = 0; r < 6; ++r) row_off[lane * 6 + r] = excl + s[r];
  if (lane == 63) Ptr[0] = excl + tot;
}

// ---------------- fill flat pair list (fallback path only) ----------------
__global__ __launch_bounds__(64) void k_fill(const int* __restrict__ row_start,
                                             const int* __restrict__ row_len,
                                             const int* __restrict__ row_off,
                                             int* __restrict__ pair_i,
                                             int* __restrict__ pair_j) {
  int i = blockIdx.x, lane = threadIdx.x;
  int s = row_start[i], len = row_len[i], off = row_off[i];
  if (lane < len) { pair_i[off + lane] = i; pair_j[off + lane] = s + lane; }
}

// =================== P3: egemm | cvt | emb (co-resident) ===================
// grid: [0,256) egemm (mt,nc) | [256,768) cvt | [768,9984) emb (2 pairs/block)
__global__ __launch_bounds__(256) void k_big(
    const float* __restrict__ Wp1, u16* __restrict__ W1H, u16* __restrict__ W1L,
    const float* __restrict__ Wp2, u16* __restrict__ W2H, u16* __restrict__ W2L,
    const float* __restrict__ Wq, u16* __restrict__ WqH,
    const float* __restrict__ Wk, u16* __restrict__ WkH,
    const float* __restrict__ Wv, u16* __restrict__ WvH,
    const float* __restrict__ mean, const float* __restrict__ Wpre,
    const float* __restrict__ bpre, float* __restrict__ event,
    const int* __restrict__ Ptr, const int* __restrict__ row_start,
    const int* __restrict__ row_off, const float* __restrict__ bbox,
    u16* __restrict__ ehi, u16* __restrict__ elo) {
  int bid = blockIdx.x, t = threadIdx.x;
  if (bid < 256) {
    // ---- event = relu(mean @ Wpre^T + bpre); B packed from f32 (same RNE as f2h) ----
    int mt = bid >> 4, nc = bid & 15;
    int w = t >> 6, lane = t & 63, lr = lane & 15, lg = lane >> 4;
    f4 acc = {};
    const float* arow = mean + (size_t)(mt * 16 + lr) * 1024;
    const float* brow = Wpre + (size_t)(nc * 64 + w * 16 + lr) * 1024;
    #pragma unroll
    for (int ks = 0; ks < 32; ++ks) {
      const float* ap = arow + ks * 32 + lg * 8;
      const float* bp = brow + ks * 32 + lg * 8;
      h8 a = pack8h(*(const float4*)ap, *(const float4*)(ap + 4));
      h8 b = pack8h(*(const float4*)bp, *(const float4*)(bp + 4));
      acc = mfma16h(a, b, acc);
    }
    #pragma unroll
    for (int r = 0; r < 4; ++r) {
      int row = mt * 16 + lg * 4 + r, cn = nc * 64 + w * 16 + lr;
      event[(size_t)row * 1024 + cn] = fmaxf(acc[r] + bpre[cn], 0.f);
    }
  } else if (bid < 768) {
    const int nW1 = 1048576, nW2 = 16384, nQ = 131072;
    const int tot = nW1 + nW2 + 3 * nQ;
    for (int i = (bid - 256) * 256 + t; i < tot; i += 512 * 256) {
      if (i < nW1) {
        float x = Wp1[i]; u16 h = f2h(x);
        W1H[i] = h; W1L[i] = f2h((x - h2f(h)) * kLoScale);
      } else if (i < nW1 + nW2) {
        int j = i - nW1; float x = Wp2[j]; u16 h = f2h(x);
        W2H[j] = h; W2L[j] = f2h((x - h2f(h)) * kLoScale);
      } else {
        int j = i - nW1 - nW2;
        int a = j / nQ, r = j % nQ;
        const float* s = (a == 0) ? Wq : (a == 1) ? Wk : Wv;
        u16* d = (a == 0) ? WqH : (a == 1) ? WkH : WvH;
        d[r] = f2h(s[r]);
      }
    }
  } else {
    int eb = bid - 768;                  // emb: 2 pairs per block
    int P = Ptr[0];
    int Pc = (P + 127) & ~127;
    if (eb * 2 >= Pc) return;
    __shared__ double As[16], Bs[16];
    __shared__ int roff[384], rstart[384];
    const double kCd = -13.287712379549449 / 256.0;
    if (t < 16) As[t] = exp2(kCd * (double)(t * 16));
    else if (t < 32) Bs[t - 16] = exp2(kCd * (double)(t - 16));
    for (int k = t; k < 384; k += 256) { roff[k] = row_off[k]; rstart[k] = row_start[k]; }
    __syncthreads();
    int p = eb * 2 + (t >> 7);
    int u = t & 127;
    int hseg = u >> 6;                   // 0: dc half, 1: dl half
    int f0 = (u & 63) * 4;               // 4 consecutive freqs per thread
    size_t ob = (size_t)p * 1024 + hseg * 512 + f0;
    if (p >= P) {
      us4 z = {0, 0, 0, 0};
      *(us4*)(ehi + ob) = z; *(us4*)(ehi + ob + 256) = z;
      *(us4*)(elo + ob) = z; *(us4*)(elo + ob + 256) = z;
      return;
    }
    int lo = 0, hi = 383;
    while (lo < hi) { int md = (lo + hi + 1) >> 1; if (roff[md] <= p) lo = md; else hi = md - 1; }
    int pi = lo, pj = rstart[lo] + (p - roff[lo]);
    double s0 = bbox[pi * 2], e0 = bbox[pi * 2 + 1];
    double s1 = bbox[pj * 2], e1 = bbox[pj * 2 + 1];
    double li = fmax(e0 - s0, 0.1), lj = fmax(e1 - s1, 0.1);
    double x = hseg ? log(lj / li) : (0.5 * (s0 + e0) - 0.5 * (s1 + e1)) / li;
    double x100 = 100.0 * x;
    const double INV2PI = 0.15915494309189535;
    const double TWOPI  = 6.283185307179586;
    us4 sh_, sl_, ch_, cl_;
    #pragma unroll
    for (int j = 0; j < 4; ++j) {
      int f = f0 + j;
      double ang = x100 * (As[f >> 4] * Bs[f & 15]);
      double nn = rint(ang * INV2PI);
      float rf = (float)fma(-nn, TWOPI, ang);
      float sv = __sinf(rf), cv = __cosf(rf);
      u16 hs = f2h(sv); sh_[j] = hs; sl_[j] = f2h((sv - h2f(hs)) * kLoScale);
      u16 hc = f2h(cv); ch_[j] = hc; cl_[j] = f2h((cv - h2f(hc)) * kLoScale);
    }
    *(us4*)(ehi + ob) = sh_; *(us4*)(ehi + ob + 256) = ch_;
    *(us4*)(elo + ob) = sl_; *(us4*)(elo + ob + 256) = cl_;
  }
}

// =================== P4: pos layer1+2 GEMM + qkv projections ===================
// grid: [0,1152) pos1 (mb = bid%144, nb = bid/144 -- emb-tile sharers land same-XCD)
//       [1152,1728) qkv (z,mt,h; 4 waves = 8 nt)
__global__ __launch_bounds__(256, 2) void k_main(
    const int* __restrict__ Ptr, const u16* __restrict__ ehi, const u16* __restrict__ elo,
    const u16* __restrict__ W1h, const u16* __restrict__ W1l, const float* __restrict__ bias1,
    const u16* __restrict__ W2h, const u16* __restrict__ W2l, float* __restrict__ bias_acc,
    const float* __restrict__ event, const int* __restrict__ eidx,
    const u16* __restrict__ WqH, const float* __restrict__ bq,
    const u16* __restrict__ WkH, const float* __restrict__ bk,
    const u16* __restrict__ WvH, const float* __restrict__ bv,
    float* __restrict__ qb, float* __restrict__ kbuf, float* __restrict__ vbuf,
    int pos_on) {
  __shared__ u16 lds[2][4][4096];
  int bid = blockIdx.x, tid = threadIdx.x;
  if (bid < 1152) {
    if (!pos_on) return;
    int P = Ptr[0];
    int mb = bid % 144, nb = bid / 144;  // 8 sharers of emb tile mb are 144 apart -> same XCD
    if (mb * 128 >= P) return;
    int w = tid >> 6, lane = tid & 63;
    int lr = lane & 15, lg = lane >> 4;
    int srow[2], scol[2];
    #pragma unroll
    for (int cc = 0; cc < 2; ++cc) {
      int c = w * 2 + cc;
      int d = c * 1024 + lane * 16;
      int b = d ^ (((((d >> 6) & 3)) ^ ((d >> 8) & 3)) << 4);
      srow[cc] = b >> 6;
      scol[cc] = b & 63;
    }
    const u16* planes[4] = {ehi, elo, W1h, W1l};
    int rb0 = mb * 128, rb1 = nb * 128;
    auto stage = [&](int buf, int k0) {
      #pragma unroll
      for (int t = 0; t < 4; ++t) {
        int rbase = (t < 2) ? rb0 : rb1;
        #pragma unroll
        for (int cc = 0; cc < 2; ++cc) {
          int c = w * 2 + cc;
          const char* src = (const char*)(planes[t] + (size_t)(rbase + srow[cc]) * 1024 + k0) + scol[cc];
          char* dst = (char*)&lds[buf][t][0] + c * 1024;
          __builtin_amdgcn_global_load_lds(
              (const __attribute__((address_space(1))) char*)src,
              (__attribute__((address_space(3))) char*)dst, 16, 0, 0);
        }
      }
    };
    stage(0, 0);
    f4 aH[4][4] = {}, aL[4][4] = {};
    int wm = (w >> 1) * 64, wn = (w & 1) * 64;
    int sl = (lg ^ (lr & 3) ^ ((lr >> 2) & 3)) << 4;   // swizzled 16B slot
    __syncthreads();
    for (int kt = 0; kt < 32; ++kt) {
      int cur = kt & 1;
      if (kt < 31) stage(cur ^ 1, (kt + 1) * 32);
      h8 ah[4], al[4], bh[4], bl[4];
      #pragma unroll
      for (int mt = 0; mt < 4; ++mt) {
        int ad = (wm + mt * 16 + lr) * 64 + sl;
        ah[mt] = *(const h8*)((const char*)&lds[cur][0][0] + ad);
        al[mt] = *(const h8*)((const char*)&lds[cur][1][0] + ad);
      }
      #pragma unroll
      for (int nt = 0; nt < 4; ++nt) {
        int ad = (wn + nt * 16 + lr) * 64 + sl;
        bh[nt] = *(const h8*)((const char*)&lds[cur][2][0] + ad);
        bl[nt] = *(const h8*)((const char*)&lds[cur][3][0] + ad);
      }
      #pragma unroll
      for (int mt = 0; mt < 4; ++mt)
        #pragma unroll
        for (int nt = 0; nt < 4; ++nt) {
          aH[mt][nt] = mfma16h(ah[mt], bh[nt], aH[mt][nt]);
          aL[mt][nt] = mfma16h(al[mt], bh[nt], aL[mt][nt]);
          aL[mt][nt] = mfma16h(ah[mt], bl[nt], aL[mt][nt]);
        }
      __syncthreads();
    }
    // ---- epilogue: z1 quadrant -> LDS (swizzled) ----
    float* zq = (float*)&lds[0][0][0] + w * 4096;   // 16KB per wave
    #pragma unroll
    for (int mt = 0; mt < 4; ++mt)
      #pragma unroll
      for (int nt = 0; nt < 4; ++nt)
        #pragma unroll
        for (int r = 0; r < 4; ++r) {
          int pl = mt * 16 + lg * 4 + r;
          int nl = nt * 16 + lr;
          float z1 = aH[mt][nt][r] + aL[mt][nt][r] * kLoInv + bias1[nb * 128 + wn + nl];
          zq[pl * 64 + (nl ^ ((pl & 7) << 3))] = fmaxf(z1, 0.f);
        }
    __syncthreads();
    // ---- layer 2: z2 partial = relu(z1) @ W2^T over this wave's 64 n ----
    f4 c2h[4], c2l[4];
    #pragma unroll
    for (int i = 0; i < 4; ++i) { c2h[i] = f4{}; c2l[i] = f4{}; }
    #pragma unroll
    for (int mt2 = 0; mt2 < 4; ++mt2) {
      #pragma unroll
      for (int kc = 0; kc < 2; ++kc) {
        int pl = mt2 * 16 + lr;
        int n0 = kc * 32 + lg * 8;
        const float* rp = zq + pl * 64 + (n0 ^ ((pl & 7) << 3));
        float4 v0 = *(const float4*)rp;
        float4 v1 = *(const float4*)(rp + 4);
        h8 ah2, al2;
        #pragma unroll
        for (int j = 0; j < 4; ++j) {
          h16 h0 = (h16)v0[j]; ah2[j] = h0;     al2[j] = (h16)((v0[j] - (float)h0) * kLoScale);
          h16 h1 = (h16)v1[j]; ah2[4 + j] = h1; al2[4 + j] = (h16)((v1[j] - (float)h1) * kLoScale);
        }
        int ng = nb * 128 + wn + n0;
        h8 bh2 = *(const h8*)(W2h + lr * 1024 + ng);
        h8 bl2 = *(const h8*)(W2l + lr * 1024 + ng);
        c2h[mt2] = mfma16h(ah2, bh2, c2h[mt2]);
        c2l[mt2] = mfma16h(al2, bh2, c2l[mt2]);
        c2l[mt2] = mfma16h(ah2, bl2, c2l[mt2]);
      }
    }
    #pragma unroll
    for (int mt2 = 0; mt2 < 4; ++mt2)
      #pragma unroll
      for (int r = 0; r < 4; ++r) {
        int p = mb * 128 + wm + mt2 * 16 + lg * 4 + r;
        if (p < P)
          atomicAdd(&bias_acc[(size_t)p * 16 + lr], c2h[mt2][r] + c2l[mt2][r] * kLoInv);
      }
  } else {
    int b2 = bid - 1152;                 // 576 blocks: z, mt, h
    int z = b2 / 192, r2 = b2 % 192, mt = r2 >> 3, h = r2 & 7;
    int w = tid >> 6, lane = tid & 63, lr = lane & 15, lg = lane >> 4;
    const u16* W = (z == 0) ? WqH : (z == 1) ? WkH : WvH;
    const float* bias = (z == 0) ? bq : (z == 1) ? bk : bv;
    float* out = (z == 0) ? qb : (z == 1) ? kbuf : vbuf;
    int row = mt * 16 + lr;
    const float* arow = event + (size_t)eidx[row] * 1024 + h * 128;
    f4 acc[2] = {};
    #pragma unroll
    for (int ks = 0; ks < 4; ++ks) {
      const float* ap = arow + ks * 32 + lg * 8;
      h8 a = pack8h(*(const float4*)ap, *(const float4*)(ap + 4));
      #pragma unroll
      for (int n2 = 0; n2 < 2; ++n2) {
        int nt = w * 2 + n2;
        h8 b = *(const h8*)(W + h * 16384 + (nt * 16 + lr) * 128 + ks * 32 + lg * 8);
        acc[n2] = mfma16h(a, b, acc[n2]);
      }
    }
    #pragma unroll
    for (int n2 = 0; n2 < 2; ++n2)
      #pragma unroll
      for (int r = 0; r < 4; ++r) {
        int rn = mt * 16 + lg * 4 + r, e = (w * 2 + n2) * 16 + lr;
        out[(size_t)rn * 1024 + h * 128 + e] = acc[n2][r] + bias[h * 128 + e];
      }
  }
}

// =================== P5: att (+inline bias finalize) + outx ===================
// grid: [0,6144) att (i = bid>>4, g = bid&15) | [6144,6528) outx
__global__ __launch_bounds__(64) void k_att(const float* __restrict__ q,
                                            const float* __restrict__ kk,
                                            const float* __restrict__ vv,
                                            const float* __restrict__ bias_acc,
                                            const float* __restrict__ bias2,
                                            const int* __restrict__ row_start,
                                            const int* __restrict__ row_len,
                                            const int* __restrict__ row_off,
                                            const float* __restrict__ event,
                                            const int* __restrict__ eidx,
                                            const float* __restrict__ bbox,
                                            float* __restrict__ dout) {
  int bid = blockIdx.x, lane = threadIdx.x;
  if (bid >= 6144) {
    int i = bid - 6144;
    const float* er = event + (size_t)eidx[i] * 1024;
    float* orow = dout + (size_t)i * kOutCols;
    #pragma unroll
    for (int it = 0; it < 4; ++it) {
      int c = lane * 4 + it * 256;
      *(float4*)(orow + c) = *(const float4*)(er + c);
    }
    for (int t = lane; t < 100; t += 64) {
      int qq = t / 25, f = t % 25;
      float x = bbox[i * 2 + (qq >> 1)];
      float ang = 100.f * x * exp2f((float)f * (-13.287712379549449f * 0.04f));
      float sv, cv;
      fsincos(ang, sv, cv);
      orow[2048 + t] = (qq & 1) ? cv : sv;
    }
    return;
  }
  int i = bid >> 4, g = bid & 15;
  int s = row_start[i], L = row_len[i], pb = row_off[i];
  __shared__ float qs[64];
  __shared__ float att[64];
  qs[lane] = q[(size_t)i * 1024 + g * 64 + lane];
  __syncthreads();
  bool valid = lane < L;
  const float* kr = kk + (size_t)(s + (valid ? lane : 0)) * 1024 + g * 64;
  float sc = 0.f;
  #pragma unroll
  for (int dt = 0; dt < 16; ++dt) {
    float4 kv = *(const float4*)(kr + dt * 4);
    sc += qs[dt * 4 + 0] * kv.x + qs[dt * 4 + 1] * kv.y +
          qs[dt * 4 + 2] * kv.z + qs[dt * 4 + 3] * kv.w;
  }
  int pidx = min(pb + lane, kMaxP - 1);
  float pbias = 0.f;
  if (valid) {
    float zs = bias_acc[(size_t)pidx * 16 + g] + bias2[g];
    pbias = logf(fmaxf(zs, 1e-6f));
  }
  sc = valid ? (sc * 0.125f + pbias) : -3.0e38f;
  float mx = sc;
  #pragma unroll
  for (int off = 32; off > 0; off >>= 1) mx = fmaxf(mx, __shfl_xor(mx, off));
  float pe = valid ? __expf(sc - mx) : 0.f;
  float sm = pe;
  #pragma unroll
  for (int off = 32; off > 0; off >>= 1) sm += __shfl_xor(sm, off);
  att[lane] = pe / sm;
  __syncthreads();
  // att@V with 4 independent partial sums (ILP over the serial FMA chain)
  float o0 = 0.f, o1 = 0.f, o2 = 0.f, o3 = 0.f;
  const float* vb = vv + (size_t)s * 1024 + g * 64 + lane;
  int jl = 0;
  for (; jl + 3 < L; jl += 4) {
    o0 += att[jl]     * vb[(size_t)jl * 1024];
    o1 += att[jl + 1] * vb[(size_t)(jl + 1) * 1024];
    o2 += att[jl + 2] * vb[(size_t)(jl + 2) * 1024];
    o3 += att[jl + 3] * vb[(size_t)(jl + 3) * 1024];
  }
  for (; jl < L; ++jl) o0 += att[jl] * vb[(size_t)jl * 1024];
  dout[(size_t)i * kOutCols + 1024 + g * 64 + lane] = (o0 + o1) + (o2 + o3);
}

// ---------------- FALLBACK fused pos kernel: writes raw z2 sum into bias_acc ----------
__global__ __launch_bounds__(256) void k_pos(
    const int* __restrict__ Ptr, const int* __restrict__ pair_i,
    const int* __restrict__ pair_j, const float* __restrict__ bbox,
    const u16* __restrict__ W1h, const u16* __restrict__ W1l,
    const float* __restrict__ bias1,
    const u16* __restrict__ W2h, const u16* __restrict__ W2l,
    float* __restrict__ bias_acc) {
  int P = Ptr[0];
  int base0 = blockIdx.x * 64;
  if (base0 >= P) return;
  int w = threadIdx.x >> 6, l = threadIdx.x & 63;
  int lr = l & 15, lg = l >> 4;
  int base = base0 + w * 16;
  int p = base + lr;
  bool valid = p < P;
  int pi = valid ? pair_i[p] : 0;
  int pj = valid ? pair_j[p] : 0;
  double s0 = bbox[pi * 2], e0 = bbox[pi * 2 + 1];
  double s1 = bbox[pj * 2], e1 = bbox[pj * 2 + 1];
  double li = fmax(e0 - s0, 0.1), lj = fmax(e1 - s1, 0.1);
  double dcd = (0.5 * (s0 + e0) - 0.5 * (s1 + e1)) / li;
  double dld = log(lj / li);
  const double kCd = -13.287712379549449 / 256.0;
  double r1  = exp2(kCd);
  double r32 = exp2(kCd * 32.0);
  double pb0 = exp2(kCd * (double)(lg * 8));
  const double INV2PI = 0.15915494309189535;
  const double TWOPI  = 6.283185307179586;
  h8 eh[32], el[32];
  #pragma unroll
  for (int hx = 0; hx < 2; ++hx) {
    double x100 = 100.0 * (hx ? dld : dcd);
    double pch = pb0;
    #pragma unroll
    for (int ksl = 0; ksl < 8; ++ksl) {
      double pp = pch;
      #pragma unroll
      for (int j = 0; j < 8; ++j) {
        double ang = x100 * pp;
        double nn = rint(ang * INV2PI);
        float rf = (float)fma(-nn, TWOPI, ang);
        float sv = __sinf(rf), cv = __cosf(rf);
        h16 sh = (h16)sv, ch = (h16)cv;
        eh[hx * 16 + ksl][j] = sh;
        el[hx * 16 + ksl][j] = (h16)((sv - (float)sh) * kLoScale);
        eh[hx * 16 + 8 + ksl][j] = ch;
        el[hx * 16 + 8 + ksl][j] = (h16)((cv - (float)ch) * kLoScale);
        pp *= r1;
      }
      pch *= r32;
    }
  }
  __shared__ float p1f[4][16 * 64];
  char* myp1 = (char*)p1f[w];
  f4 acc2 = {}, acc2l = {};
  for (int nc = 0; nc < 16; ++nc) {
    f4 accH[4] = {}, accL[4] = {};
    #pragma unroll
    for (int ks = 0; ks < 32; ++ks) {
      #pragma unroll
      for (int nt = 0; nt < 4; ++nt) {
        size_t boff = (size_t)(nc * 64 + nt * 16 + lr) * 1024 + ks * 32 + lg * 8;
        h8 bh = *(const h8*)(W1h + boff);
        h8 bl = *(const h8*)(W1l + boff);
        accH[nt] = mfma16h(eh[ks], bh, accH[nt]);
        accL[nt] = mfma16h(el[ks], bh, accL[nt]);
        accL[nt] = mfma16h(eh[ks], bl, accL[nt]);
      }
    }
    __syncthreads();
    #pragma unroll
    for (int nt = 0; nt < 4; ++nt)
      #pragma unroll
      for (int r = 0; r < 4; ++r) {
        int m = lg * 4 + r, n = nt * 16 + lr;
        float z1 = accH[nt][r] + accL[nt][r] * kLoInv + bias1[nc * 64 + n];
        int byte = ((m * 64 + n) * 4) ^ ((m & 7) << 4);
        *(float*)(myp1 + byte) = fmaxf(z1, 0.f);
      }
    __syncthreads();
    #pragma unroll
    for (int hf = 0; hf < 2; ++hf) {
      int kb = hf * 32 + lg * 8;
      int b0 = ((lr * 64 + kb) * 4) ^ ((lr & 7) << 4);
      int b1 = ((lr * 64 + kb + 4) * 4) ^ ((lr & 7) << 4);
      float4 x0 = *(const float4*)(myp1 + b0);
      float4 x1 = *(const float4*)(myp1 + b1);
      h8 ah, al;
      #pragma unroll
      for (int j = 0; j < 4; ++j) {
        h16 h0 = (h16)x0[j];
        ah[j] = h0; al[j] = (h16)((x0[j] - (float)h0) * kLoScale);
        h16 h1 = (h16)x1[j];
        ah[4 + j] = h1; al[4 + j] = (h16)((x1[j] - (float)h1) * kLoScale);
      }
      h8 bh = *(const h8*)(W2h + lr * 1024 + nc * 64 + kb);
      h8 bl = *(const h8*)(W2l + lr * 1024 + nc * 64 + kb);
      acc2  = mfma16h(ah, bh, acc2);
      acc2l = mfma16h(al, bh, acc2l);
      acc2l = mfma16h(ah, bl, acc2l);
    }
  }
  #pragma unroll
  for (int r = 0; r < 4; ++r) {
    int m = lg * 4 + r;
    int pp = base + m;
    if (pp < P)
      bias_acc[(size_t)pp * 16 + lr] = acc2[r] + acc2l[r] * kLoInv;
  }
}

extern "C" void kernel_launch(void* const* d_in, const int* in_sizes, int n_in,
                              void* d_out, int out_size, void* d_ws, size_t ws_size,
                              hipStream_t stream) {
  const float* feats = (const float*)d_in[0];
  const int*   gidx  = (const int*)d_in[1];
  const float* cmask = (const float*)d_in[2];
  const int*   eidx  = (const int*)d_in[3];
  const float* bmask = (const float*)d_in[4];
  const float* bbox  = (const float*)d_in[5];
  const float* Wpre  = (const float*)d_in[6];
  const float* bpre  = (const float*)d_in[7];
  const float* Wq    = (const float*)d_in[8];
  const float* bq    = (const float*)d_in[9];
  const float* Wk    = (const float*)d_in[10];
  const float* bk    = (const float*)d_in[11];
  const float* Wv    = (const float*)d_in[12];
  const float* bv    = (const float*)d_in[13];
  const float* Wp1   = (const float*)d_in[14];
  const float* bp1   = (const float*)d_in[15];
  const float* Wp2   = (const float*)d_in[16];
  const float* bp2   = (const float*)d_in[17];

  char* ws = (char*)d_ws;
  size_t off = 0;
  auto alloc = [&](size_t bytes) {
    char* r = ws + off;
    off += (bytes + 255) & ~(size_t)255;
    return r;
  };
  // ---- base allocations ----
  u16* W1H   = (u16*)alloc((size_t)1048576 * 2);
  u16* W1L   = (u16*)alloc((size_t)1048576 * 2);
  u16* W2H   = (u16*)alloc((size_t)16384 * 2);
  u16* W2L   = (u16*)alloc((size_t)16384 * 2);
  u16* WqH   = (u16*)alloc((size_t)131072 * 2);
  u16* WkH   = (u16*)alloc((size_t)131072 * 2);
  u16* WvH   = (u16*)alloc((size_t)131072 * 2);
  float* mean  = (float*)alloc((size_t)256 * 1024 * 4);
  float* event = (float*)alloc((size_t)256 * 1024 * 4);
  float* qb    = (float*)alloc((size_t)384 * 1024 * 4);
  float* kb    = (float*)alloc((size_t)384 * 1024 * 4);
  float* vb    = (float*)alloc((size_t)384 * 1024 * 4);
  int* row_start = (int*)alloc(kN * 4);
  int* row_len   = (int*)alloc(kN * 4);
  int* row_off   = (int*)alloc(kN * 4);
  int* Ptr       = (int*)alloc(256);
  int* pair_i    = (int*)alloc((size_t)kMaxP * 4);
  int* pair_j    = (int*)alloc((size_t)kMaxP * 4);
  float* bias_acc = (float*)alloc((size_t)kMaxP * 16 * 4);
  // ---- extended (fast-path) allocations ----
  u16* ehi      = (u16*)alloc((size_t)kMaxP * 1024 * 2);
  u16* elo      = (u16*)alloc((size_t)kMaxP * 1024 * 2);
  bool fast = (off <= ws_size);

  k_pre<<<400, 256, 0, stream>>>(bmask, row_start, row_len,
                                 feats, gidx, cmask, mean, bias_acc);
  k_scan<<<1, 64, 0, stream>>>(row_len, row_off, Ptr);
  k_big<<<9984, 256, 0, stream>>>(Wp1, W1H, W1L, Wp2, W2H, W2L,
                                  Wq, WqH, Wk, WkH, Wv, WvH,
                                  mean, Wpre, bpre, event,
                                  Ptr, row_start, row_off, bbox, ehi, elo);

  if (fast) {
    k_main<<<1728, 256, 0, stream>>>(Ptr, ehi, elo, W1H, W1L, bp1, W2H, W2L, bias_acc,
                                     event, eidx, WqH, bq, WkH, bk, WvH, bv,
                                     qb, kb, vb, 1);
  } else {
    k_fill<<<kN, 64, 0, stream>>>(row_start, row_len, row_off, pair_i, pair_j);
    k_pos<<<kMaxP / 64, 256, 0, stream>>>(Ptr, pair_i, pair_j, bbox, W1H, W1L, bp1,
                                          W2H, W2L, bias_acc);
    k_main<<<1728, 256, 0, stream>>>(Ptr, ehi, elo, W1H, W1L, bp1, W2H, W2L, bias_acc,
                                     event, eidx, WqH, bq, WkH, bk, WvH, bv,
                                     qb, kb, vb, 0);
  }
  k_att<<<6528, 64, 0, stream>>>(qb, kb, vb, bias_acc, bp2, row_start, row_len, row_off,
                                 event, eidx, bbox, (float*)d_out);
}